// Round 3
// baseline (2416.605 us; speedup 1.0000x reference)
//
#include <hip/hip_runtime.h>

// GCN, bucket-binned gather aggregation (no node-granular scatter):
//   bucket = dst >> 7  (128 nodes/bucket, NB = ceil(N/128) buckets)
//   1) bucket hist + scan; scatter packed (src | local<<17) into bucket regions
//   2) deg_inv from binned pairs (LDS hist per bucket, coalesced write)
//   3) agg1 = sum X[src] per node  (block per bucket x channel-half, LDS accum)
//   4) h  = relu((deg_inv*agg1) @ W1 + b1)   (prescale folded into GEMM staging)
//   5) m2 = h @ W2
//   6) out = deg_inv * sum m2[src] + b2      (fused epilogue in agg)
// Requires N <= 2^17 (src packed in 17 bits). N = 100000 here.

__global__ __launch_bounds__(256) void k_bhist(
    const int* __restrict__ dst, int* __restrict__ bcnt, int E, int NB)
{
    __shared__ int sh[1024];
    for (int i = threadIdx.x; i < NB; i += 256) sh[i] = 0;
    __syncthreads();
    for (int e = blockIdx.x * 256 + threadIdx.x; e < E; e += gridDim.x * 256)
        atomicAdd(&sh[dst[e] >> 7], 1);
    __syncthreads();
    for (int i = threadIdx.x; i < NB; i += 256) {
        const int v = sh[i];
        if (v) atomicAdd(&bcnt[i], v);
    }
}

__global__ __launch_bounds__(1024) void k_bscan(
    const int* __restrict__ bcnt, int* __restrict__ bstart,
    int* __restrict__ bcursor, int NB, int E)
{
    __shared__ int sh[1024];
    const int t = threadIdx.x;
    const int v = (t < NB) ? bcnt[t] : 0;
    sh[t] = v;
    __syncthreads();
    for (int off = 1; off < 1024; off <<= 1) {
        int u = (t >= off) ? sh[t - off] : 0;
        __syncthreads();
        if (t >= off) sh[t] += u;
        __syncthreads();
    }
    if (t < NB) {
        const int ex = sh[t] - v;
        bstart[t] = ex;
        bcursor[t] = ex;
    }
    if (t == 0) bstart[NB] = E;
}

__global__ __launch_bounds__(256) void k_bscatter(
    const int* __restrict__ src, const int* __restrict__ dst,
    int* __restrict__ bcursor, unsigned* __restrict__ pairs, int E)
{
    const int e = blockIdx.x * 256 + threadIdx.x;
    if (e >= E) return;
    const int d = dst[e];
    const int p = atomicAdd(&bcursor[d >> 7], 1);
    pairs[p] = (unsigned)src[e] | ((unsigned)(d & 127) << 17);
}

__global__ __launch_bounds__(256) void k_deg(
    const unsigned* __restrict__ pairs, const int* __restrict__ bstart,
    float* __restrict__ dinv, int N)
{
    __shared__ int cnt[128];
    const int b = blockIdx.x;
    if (threadIdx.x < 128) cnt[threadIdx.x] = 0;
    __syncthreads();
    const int beg = bstart[b], end = bstart[b + 1];
    for (int j = beg + threadIdx.x; j < end; j += 256)
        atomicAdd(&cnt[pairs[j] >> 17], 1);
    __syncthreads();
    if (threadIdx.x < 128) {
        const int node = b * 128 + threadIdx.x;
        if (node < N) dinv[node] = 1.0f / fmaxf((float)cnt[threadIdx.x], 1.0f);
    }
}

// Block handles one (bucket, 64-channel slice): LDS accum 128x64 f32.
// LDM: row stride of M. CS: channel-slices per bucket (128ch->2, 64ch->1).
// EPI: multiply deg_inv and add bias on writeback (layer-2 epilogue).
template<int LDM, int CS, bool EPI>
__global__ __launch_bounds__(256) void k_agg(
    const float* __restrict__ M, const unsigned* __restrict__ pairs,
    const int* __restrict__ bstart, const float* __restrict__ dinv,
    const float* __restrict__ bias, float* __restrict__ outp, int ldo, int N)
{
    __shared__ float acc[128][64];   // 32 KiB
    __shared__ unsigned ep[512];     // staged pairs
    const int b  = blockIdx.x / CS;
    const int cb = blockIdx.x % CS;
    const int tid = threadIdx.x;
    const int lane = tid & 63;
    const int wid = tid >> 6;
    const int c0 = cb * 64;

    for (int i = tid; i < 128 * 16; i += 256)
        ((float4*)&acc[0][0])[i] = make_float4(0.f, 0.f, 0.f, 0.f);
    const int beg = bstart[b], end = bstart[b + 1];
    __syncthreads();

    for (int base = beg; base < end; base += 512) {
        const int cnt = min(512, end - base);
        for (int i = tid; i < cnt; i += 256) ep[i] = pairs[base + i];
        __syncthreads();
        for (int j0 = wid * 4; j0 < cnt; j0 += 16) {
            const int m = min(4, cnt - j0);
            float v0 = 0.f, v1 = 0.f, v2 = 0.f, v3 = 0.f;
            int l0 = 0, l1 = 0, l2 = 0, l3 = 0;
            unsigned pr;
            pr = ep[j0]; l0 = pr >> 17;
            v0 = M[(size_t)(pr & 0x1FFFFu) * LDM + c0 + lane];
            if (m > 1) { pr = ep[j0 + 1]; l1 = pr >> 17;
                v1 = M[(size_t)(pr & 0x1FFFFu) * LDM + c0 + lane]; }
            if (m > 2) { pr = ep[j0 + 2]; l2 = pr >> 17;
                v2 = M[(size_t)(pr & 0x1FFFFu) * LDM + c0 + lane]; }
            if (m > 3) { pr = ep[j0 + 3]; l3 = pr >> 17;
                v3 = M[(size_t)(pr & 0x1FFFFu) * LDM + c0 + lane]; }
            atomicAdd(&acc[l0][lane], v0);
            if (m > 1) atomicAdd(&acc[l1][lane], v1);
            if (m > 2) atomicAdd(&acc[l2][lane], v2);
            if (m > 3) atomicAdd(&acc[l3][lane], v3);
        }
        __syncthreads();
    }

    for (int i = tid; i < 128 * 16; i += 256) {
        const int r = i >> 4;
        const int cc = (i & 15) << 2;
        const int node = b * 128 + r;
        if (node >= N) continue;
        float4 o = *(const float4*)&acc[r][cc];
        if (EPI) {
            const float s = dinv[node];
            const float4 bv = *(const float4*)(bias + c0 + cc);
            o.x = fmaf(o.x, s, bv.x);
            o.y = fmaf(o.y, s, bv.y);
            o.z = fmaf(o.z, s, bv.z);
            o.w = fmaf(o.w, s, bv.w);
        }
        *(float4*)(outp + (size_t)node * ldo + c0 + cc) = o;
    }
}

// C[row,0:OUTC] = (opt dinv[row]*) A[row,0:128] @ W[128,OUTC] (+opt bias&relu).
// 64 rows/block, 256 threads, A tile in LDS. In-place safe.
template<int OUTC, bool PRESCALE, bool BIASRELU>
__global__ __launch_bounds__(256) void k_gemm(
    const float* __restrict__ A, const float* __restrict__ W,
    const float* __restrict__ bias, const float* __restrict__ deg_inv,
    float* __restrict__ C, int N, int out_stride)
{
    __shared__ float As[64][128];
    const int tid = threadIdx.x;
    const int row0 = blockIdx.x * 64;

    for (int i = tid; i < 64 * 32; i += 256) {
        const int r = i >> 5;
        const int cc = (i & 31) << 2;
        const int row = row0 + r;
        float4 v = make_float4(0.f, 0.f, 0.f, 0.f);
        if (row < N) {
            v = *(const float4*)(A + (size_t)row * 128 + cc);
            if (PRESCALE) {
                const float s = deg_inv[row];
                v.x *= s; v.y *= s; v.z *= s; v.w *= s;
            }
        }
        *(float4*)&As[r][cc] = v;
    }
    __syncthreads();

    constexpr int CG = OUTC / 4;
    constexpr int RPT = (64 * CG) / 256;
    const int cg = tid & (CG - 1);
    const int rg = tid / CG;
    const int c0 = cg * 4;
    const int r0 = rg * RPT;

    float acc[RPT][4];
#pragma unroll
    for (int r = 0; r < RPT; ++r)
        for (int j = 0; j < 4; ++j) acc[r][j] = 0.f;

#pragma unroll 2
    for (int k = 0; k < 128; k += 4) {
        const float4 w0 = *(const float4*)(W + (size_t)(k + 0) * OUTC + c0);
        const float4 w1 = *(const float4*)(W + (size_t)(k + 1) * OUTC + c0);
        const float4 w2 = *(const float4*)(W + (size_t)(k + 2) * OUTC + c0);
        const float4 w3 = *(const float4*)(W + (size_t)(k + 3) * OUTC + c0);
#pragma unroll
        for (int r = 0; r < RPT; ++r) {
            const float4 a = *(const float4*)&As[r0 + r][k];
            acc[r][0] = fmaf(a.x, w0.x, fmaf(a.y, w1.x, fmaf(a.z, w2.x, fmaf(a.w, w3.x, acc[r][0]))));
            acc[r][1] = fmaf(a.x, w0.y, fmaf(a.y, w1.y, fmaf(a.z, w2.y, fmaf(a.w, w3.y, acc[r][1]))));
            acc[r][2] = fmaf(a.x, w0.z, fmaf(a.y, w1.z, fmaf(a.z, w2.z, fmaf(a.w, w3.z, acc[r][2]))));
            acc[r][3] = fmaf(a.x, w0.w, fmaf(a.y, w1.w, fmaf(a.z, w2.w, fmaf(a.w, w3.w, acc[r][3]))));
        }
    }

#pragma unroll
    for (int r = 0; r < RPT; ++r) {
        const int row = row0 + r0 + r;
        if (row >= N) continue;
        float4 o = make_float4(acc[r][0], acc[r][1], acc[r][2], acc[r][3]);
        if (BIASRELU) {
            const float4 b = *(const float4*)(bias + c0);
            o.x = fmaxf(o.x + b.x, 0.f);
            o.y = fmaxf(o.y + b.y, 0.f);
            o.z = fmaxf(o.z + b.z, 0.f);
            o.w = fmaxf(o.w + b.w, 0.f);
        }
        *(float4*)(C + (size_t)row * out_stride + c0) = o;
    }
}

extern "C" void kernel_launch(void* const* d_in, const int* in_sizes, int n_in,
                              void* d_out, int out_size, void* d_ws, size_t ws_size,
                              hipStream_t stream)
{
    const float* X  = (const float*)d_in[0];
    const int*  src = (const int*)d_in[1];
    const int*  dst = (const int*)d_in[2];
    const float* W1 = (const float*)d_in[3];
    const float* b1 = (const float*)d_in[4];
    const float* W2 = (const float*)d_in[5];
    const float* b2 = (const float*)d_in[6];
    float* out = (float*)d_out;

    const int N = in_sizes[0] / 128;
    const int E = in_sizes[1];
    const int NB = (N + 127) / 128;

    float* buf1 = (float*)d_ws;                          // N*128: agg1 -> h
    float* m2   = buf1 + (size_t)N * 128;                // N*64
    float* dinv = m2 + (size_t)N * 64;                   // N
    unsigned* pairs = (unsigned*)(dinv + N);             // E
    int* bcnt    = (int*)(pairs + E);                    // NB
    int* bstart  = bcnt + NB;                            // NB+1
    int* bcursor = bstart + NB + 1;                      // NB

    hipMemsetAsync(bcnt, 0, (size_t)NB * sizeof(int), stream);

    // --- bucket-binned edge layout ---
    k_bhist<<<1024, 256, 0, stream>>>(dst, bcnt, E, NB);
    k_bscan<<<1, 1024, 0, stream>>>(bcnt, bstart, bcursor, NB, E);
    k_bscatter<<<(E + 255) / 256, 256, 0, stream>>>(src, dst, bcursor, pairs, E);
    k_deg<<<NB, 256, 0, stream>>>(pairs, bstart, dinv, N);

    // --- layer 1: gather-agg (unscaled), then GEMM with prescale+bias+relu ---
    k_agg<128, 2, false><<<NB * 2, 256, 0, stream>>>(X, pairs, bstart, nullptr, nullptr, buf1, 128, N);
    k_gemm<128, true, true><<<(N + 63) / 64, 256, 0, stream>>>(buf1, W1, b1, dinv, buf1, N, 128);

    // --- layer 2: GEMM, then gather-agg with fused deg_inv+bias epilogue ---
    k_gemm<64, false, false><<<(N + 63) / 64, 256, 0, stream>>>(buf1, W2, nullptr, nullptr, m2, N, 64);
    k_agg<64, 1, true><<<NB, 256, 0, stream>>>(m2, pairs, bstart, dinv, b2, out, 64, N);
}

// Round 4
// 691.255 us; speedup vs baseline: 3.4960x; 3.4960x over previous
//
#include <hip/hip_runtime.h>

// GCN via two-level CSR build + wave-per-node gather aggregation:
//   bucket = dst >> 7 (128 nodes/bucket); NB = ceil(N/128) <= 1024
//   1) k_bhist/k_bscan: bucket histogram + exclusive scan
//   2) k_bscatter: pack (src | local<<17) into bucket-contiguous windows
//   3) k_sort: per-bucket LDS counting sort -> edge_src (dst-sorted), row_start
//   4) agg1[n] = (1/deg) * sum X[src]            (wave per node)
//   5) h  = relu(agg1 @ W1 + b1)                 (LDS-tiled fp32 GEMM)
//   6) m2 = h @ W2
//   7) out[n] = (1/deg) * sum m2[src] + b2       (wave per node, fused epi)
// Requires N <= 2^17 (17-bit src pack). N = 100000 here.

constexpr int CAP = 6144;   // max edges/bucket on LDS fast path (avg ~2048)

__global__ __launch_bounds__(256) void k_bhist(
    const int* __restrict__ dst, int* __restrict__ bcnt, int E, int NB)
{
    __shared__ int sh[1024];
    for (int i = threadIdx.x; i < NB; i += 256) sh[i] = 0;
    __syncthreads();
    for (int e = blockIdx.x * 256 + threadIdx.x; e < E; e += gridDim.x * 256)
        atomicAdd(&sh[dst[e] >> 7], 1);
    __syncthreads();
    for (int i = threadIdx.x; i < NB; i += 256) {
        const int v = sh[i];
        if (v) atomicAdd(&bcnt[i], v);
    }
}

__global__ __launch_bounds__(1024) void k_bscan(
    const int* __restrict__ bcnt, int* __restrict__ bstart,
    int* __restrict__ bcursor, int NB, int E)
{
    __shared__ int sh[1024];
    const int t = threadIdx.x;
    const int v = (t < NB) ? bcnt[t] : 0;
    sh[t] = v;
    __syncthreads();
    for (int off = 1; off < 1024; off <<= 1) {
        int u = (t >= off) ? sh[t - off] : 0;
        __syncthreads();
        if (t >= off) sh[t] += u;
        __syncthreads();
    }
    if (t < NB) {
        const int ex = sh[t] - v;
        bstart[t] = ex;
        bcursor[t] = ex;
    }
    if (t == 0) bstart[NB] = E;
}

__global__ __launch_bounds__(256) void k_bscatter(
    const int* __restrict__ src, const int* __restrict__ dst,
    int* __restrict__ bcursor, unsigned* __restrict__ pairs, int E)
{
    const int e = blockIdx.x * 256 + threadIdx.x;
    if (e >= E) return;
    const int d = dst[e];
    const int p = atomicAdd(&bcursor[d >> 7], 1);
    pairs[p] = (unsigned)src[e] | ((unsigned)(d & 127) << 17);
}

// One block per bucket: LDS counting sort of the bucket's pairs by local node.
// Emits edge_src (coalesced) and node-level row_start; row-major deg implied.
__global__ __launch_bounds__(256) void k_sort(
    const unsigned* __restrict__ pairs, const int* __restrict__ bstart,
    int* __restrict__ edge_src, int* __restrict__ row_start, int N, int E)
{
    __shared__ unsigned sp[CAP];
    __shared__ int sorted[CAP];
    __shared__ int lcnt[128];
    __shared__ int ls[128];
    const int b = blockIdx.x;
    const int tid = threadIdx.x;
    const int beg = bstart[b], end = bstart[b + 1];
    const int cnt = end - beg;
    const bool fits = (cnt <= CAP);

    if (tid < 128) lcnt[tid] = 0;
    __syncthreads();

    if (fits) {
        for (int i = tid; i < cnt; i += 256) {
            const unsigned p = pairs[beg + i];
            sp[i] = p;
            atomicAdd(&lcnt[p >> 17], 1);
        }
    } else {
        for (int i = tid; i < cnt; i += 256)
            atomicAdd(&lcnt[pairs[beg + i] >> 17], 1);
    }
    __syncthreads();

    // inclusive scan of lcnt -> ls (128 entries, Hillis-Steele)
    if (tid < 128) ls[tid] = lcnt[tid];
    __syncthreads();
    for (int off = 1; off < 128; off <<= 1) {
        int v = 0;
        if (tid < 128 && tid >= off) v = ls[tid - off];
        __syncthreads();
        if (tid < 128 && tid >= off) ls[tid] += v;
        __syncthreads();
    }

    // row_start for this bucket's nodes (exclusive = ls - lcnt)
    if (tid < 128) {
        const int node = b * 128 + tid;
        if (node <= N) row_start[node] = beg + ls[tid] - lcnt[tid];
    }
    if (b == 0 && tid == 0) row_start[N] = E;   // covers N % 128 == 0 too
    __syncthreads();

    // cursors = exclusive starts (reuse ls)
    if (tid < 128) ls[tid] -= lcnt[tid];
    __syncthreads();

    if (fits) {
        for (int i = tid; i < cnt; i += 256) {
            const unsigned p = sp[i];
            const int pos = atomicAdd(&ls[p >> 17], 1);
            sorted[pos] = (int)(p & 0x1FFFFu);
        }
        __syncthreads();
        for (int i = tid; i < cnt; i += 256) edge_src[beg + i] = sorted[i];
    } else {
        for (int i = tid; i < cnt; i += 256) {
            const unsigned p = pairs[beg + i];
            const int pos = atomicAdd(&ls[p >> 17], 1);
            edge_src[beg + pos] = (int)(p & 0x1FFFFu);
        }
    }
}

// One wave per node: acc = (1/deg) * sum_{j in [beg,end)} M[edge_src[j]]  (+bias)
template<int C, bool ADDBIAS>
__global__ __launch_bounds__(256) void k_agg(
    const float* __restrict__ M, const int* __restrict__ edge_src,
    const int* __restrict__ row_start, const float* __restrict__ bias,
    float* __restrict__ outp, int N)
{
    const int w = (blockIdx.x * 256 + threadIdx.x) >> 6;
    if (w >= N) return;
    const int lane = threadIdx.x & 63;
    const int beg = row_start[w];
    const int end = row_start[w + 1];
    const float inv = 1.0f / fmaxf((float)(end - beg), 1.0f);

    if (C == 128) {
        const int c = lane * 2;
        float ax = 0.f, ay = 0.f, bx = 0.f, by = 0.f;
        int j = beg;
        for (; j + 3 < end; j += 4) {
            const int s0 = edge_src[j + 0], s1 = edge_src[j + 1];
            const int s2 = edge_src[j + 2], s3 = edge_src[j + 3];
            const float2 v0 = *(const float2*)(M + (size_t)s0 * 128 + c);
            const float2 v1 = *(const float2*)(M + (size_t)s1 * 128 + c);
            const float2 v2 = *(const float2*)(M + (size_t)s2 * 128 + c);
            const float2 v3 = *(const float2*)(M + (size_t)s3 * 128 + c);
            ax += v0.x + v2.x; ay += v0.y + v2.y;
            bx += v1.x + v3.x; by += v1.y + v3.y;
        }
        for (; j < end; ++j) {
            const float2 v = *(const float2*)(M + (size_t)edge_src[j] * 128 + c);
            ax += v.x; ay += v.y;
        }
        float2 o;
        o.x = (ax + bx) * inv;
        o.y = (ay + by) * inv;
        *(float2*)(outp + (size_t)w * 128 + c) = o;
    } else {
        float a = 0.f, b = 0.f, cc = 0.f, d = 0.f;
        int j = beg;
        for (; j + 3 < end; j += 4) {
            a  += M[(size_t)edge_src[j + 0] * 64 + lane];
            b  += M[(size_t)edge_src[j + 1] * 64 + lane];
            cc += M[(size_t)edge_src[j + 2] * 64 + lane];
            d  += M[(size_t)edge_src[j + 3] * 64 + lane];
        }
        for (; j < end; ++j) a += M[(size_t)edge_src[j] * 64 + lane];
        float o = (a + b + cc + d) * inv;
        if (ADDBIAS) o += bias[lane];
        outp[(size_t)w * 64 + lane] = o;
    }
}

// C[row, 0:OUTC] = A[row, 0:128] @ W[128, OUTC] (+ bias&relu). 64 rows/block,
// 256 threads, A tile in LDS. In-place safe (full tile staged before writes).
template<int OUTC, bool BIASRELU>
__global__ __launch_bounds__(256) void k_gemm(
    const float* __restrict__ A, const float* __restrict__ W,
    const float* __restrict__ bias, float* __restrict__ C, int N, int out_stride)
{
    __shared__ float As[64][128];
    const int tid = threadIdx.x;
    const int row0 = blockIdx.x * 64;

    for (int i = tid; i < 64 * 32; i += 256) {
        const int r = i >> 5;
        const int cc = (i & 31) << 2;
        const int row = row0 + r;
        float4 v = make_float4(0.f, 0.f, 0.f, 0.f);
        if (row < N) v = *(const float4*)(A + (size_t)row * 128 + cc);
        *(float4*)&As[r][cc] = v;
    }
    __syncthreads();

    constexpr int CG = OUTC / 4;
    constexpr int RPT = (64 * CG) / 256;
    const int cg = tid & (CG - 1);
    const int rg = tid / CG;
    const int c0 = cg * 4;
    const int r0 = rg * RPT;

    float acc[RPT][4];
#pragma unroll
    for (int r = 0; r < RPT; ++r)
        for (int j = 0; j < 4; ++j) acc[r][j] = 0.f;

#pragma unroll 2
    for (int k = 0; k < 128; k += 4) {
        const float4 w0 = *(const float4*)(W + (size_t)(k + 0) * OUTC + c0);
        const float4 w1 = *(const float4*)(W + (size_t)(k + 1) * OUTC + c0);
        const float4 w2 = *(const float4*)(W + (size_t)(k + 2) * OUTC + c0);
        const float4 w3 = *(const float4*)(W + (size_t)(k + 3) * OUTC + c0);
#pragma unroll
        for (int r = 0; r < RPT; ++r) {
            const float4 a = *(const float4*)&As[r0 + r][k];
            acc[r][0] = fmaf(a.x, w0.x, fmaf(a.y, w1.x, fmaf(a.z, w2.x, fmaf(a.w, w3.x, acc[r][0]))));
            acc[r][1] = fmaf(a.x, w0.y, fmaf(a.y, w1.y, fmaf(a.z, w2.y, fmaf(a.w, w3.y, acc[r][1]))));
            acc[r][2] = fmaf(a.x, w0.z, fmaf(a.y, w1.z, fmaf(a.z, w2.z, fmaf(a.w, w3.z, acc[r][2]))));
            acc[r][3] = fmaf(a.x, w0.w, fmaf(a.y, w1.w, fmaf(a.z, w2.w, fmaf(a.w, w3.w, acc[r][3]))));
        }
    }

#pragma unroll
    for (int r = 0; r < RPT; ++r) {
        const int row = row0 + r0 + r;
        if (row >= N) continue;
        float4 o = make_float4(acc[r][0], acc[r][1], acc[r][2], acc[r][3]);
        if (BIASRELU) {
            const float4 b = *(const float4*)(bias + c0);
            o.x = fmaxf(o.x + b.x, 0.f);
            o.y = fmaxf(o.y + b.y, 0.f);
            o.z = fmaxf(o.z + b.z, 0.f);
            o.w = fmaxf(o.w + b.w, 0.f);
        }
        *(float4*)(C + (size_t)row * out_stride + c0) = o;
    }
}

extern "C" void kernel_launch(void* const* d_in, const int* in_sizes, int n_in,
                              void* d_out, int out_size, void* d_ws, size_t ws_size,
                              hipStream_t stream)
{
    const float* X  = (const float*)d_in[0];
    const int*  src = (const int*)d_in[1];
    const int*  dst = (const int*)d_in[2];
    const float* W1 = (const float*)d_in[3];
    const float* b1 = (const float*)d_in[4];
    const float* W2 = (const float*)d_in[5];
    const float* b2 = (const float*)d_in[6];
    float* out = (float*)d_out;

    const int N = in_sizes[0] / 128;
    const int E = in_sizes[1];
    const int NB = (N + 127) / 128;

    float* buf1 = (float*)d_ws;                          // N*128: agg1 -> h
    unsigned* pairs = (unsigned*)buf1;                   // aliases buf1 (dead before agg1)
    float* m2       = buf1 + (size_t)N * 128;            // N*64
    int* edge_src   = (int*)(m2 + (size_t)N * 64);       // E
    int* row_start  = edge_src + E;                      // N+1
    int* bcnt       = row_start + N + 1;                 // NB
    int* bstart     = bcnt + NB;                         // NB+1
    int* bcursor    = bstart + NB + 1;                   // NB

    hipMemsetAsync(bcnt, 0, (size_t)NB * sizeof(int), stream);

    // --- CSR build: bucket hist -> scan -> bucket scatter -> LDS sort ---
    k_bhist<<<256, 256, 0, stream>>>(dst, bcnt, E, NB);
    k_bscan<<<1, 1024, 0, stream>>>(bcnt, bstart, bcursor, NB, E);
    k_bscatter<<<(E + 255) / 256, 256, 0, stream>>>(src, dst, bcursor, pairs, E);
    k_sort<<<NB, 256, 0, stream>>>(pairs, bstart, edge_src, row_start, N, E);

    // --- layer 1: gather-agg (scaled), then GEMM+bias+relu ---
    k_agg<128, false><<<(N + 3) / 4, 256, 0, stream>>>(X, edge_src, row_start, nullptr, buf1, N);
    k_gemm<128, true><<<(N + 63) / 64, 256, 0, stream>>>(buf1, W1, b1, buf1, N, 128);

    // --- layer 2: GEMM, then gather-agg with fused (1/deg, +b2) epilogue ---
    k_gemm<64, false><<<(N + 63) / 64, 256, 0, stream>>>(buf1, W2, nullptr, m2, N, 64);
    k_agg<64, true><<<(N + 3) / 4, 256, 0, stream>>>(m2, edge_src, row_start, b2, out, N);
}

// Round 5
// 337.268 us; speedup vs baseline: 7.1652x; 2.0496x over previous
//
#include <hip/hip_runtime.h>

// GCN via two-level CSR build + wave-per-node gather aggregation:
//   bucket = dst >> 7 (128 nodes/bucket); NB = ceil(N/128) <= 1024
//   1) k_bhist/k_bscan: bucket histogram + exclusive scan
//   2) k_binscatter: per-block LDS hist -> bulk cursor reservation -> scatter
//      packed (src | local<<17) into block-private runs (low atomic contention)
//   3) k_sort: per-bucket LDS counting sort -> edge_src (dst-sorted), row_start
//   4) agg1[n] = (1/deg) * sum X[src]            (wave per node)
//   5) h  = relu(agg1 @ W1 + b1)                 (LDS-tiled fp32 GEMM)
//   6) m2 = h @ W2
//   7) out[n] = (1/deg) * sum m2[src] + b2       (wave per node, fused epi)
// Requires N <= 2^17 (17-bit src pack). N = 100000 here.

constexpr int CAP = 6144;      // max edges/bucket on LDS sort fast path
constexpr int CHUNK = 8192;    // edges per binscatter block

__global__ __launch_bounds__(256) void k_bhist(
    const int* __restrict__ dst, int* __restrict__ bcnt, int E, int NB)
{
    __shared__ int sh[1024];
    for (int i = threadIdx.x; i < NB; i += 256) sh[i] = 0;
    __syncthreads();
    for (int e = blockIdx.x * 256 + threadIdx.x; e < E; e += gridDim.x * 256)
        atomicAdd(&sh[dst[e] >> 7], 1);
    __syncthreads();
    for (int i = threadIdx.x; i < NB; i += 256) {
        const int v = sh[i];
        if (v) atomicAdd(&bcnt[i], v);
    }
}

__global__ __launch_bounds__(1024) void k_bscan(
    const int* __restrict__ bcnt, int* __restrict__ bstart,
    int* __restrict__ bcursor, int NB, int E)
{
    __shared__ int sh[1024];
    const int t = threadIdx.x;
    const int v = (t < NB) ? bcnt[t] : 0;
    sh[t] = v;
    __syncthreads();
    for (int off = 1; off < 1024; off <<= 1) {
        int u = (t >= off) ? sh[t - off] : 0;
        __syncthreads();
        if (t >= off) sh[t] += u;
        __syncthreads();
    }
    if (t < NB) {
        const int ex = sh[t] - v;
        bstart[t] = ex;
        bcursor[t] = ex;
    }
    if (t == 0) bstart[NB] = E;
}

// Per-block: LDS hist of chunk -> one global atomic per non-empty bucket to
// reserve a contiguous run -> scatter via LDS rank cursors (block-private).
__global__ __launch_bounds__(256) void k_binscatter(
    const int* __restrict__ src, const int* __restrict__ dst,
    int* __restrict__ bcursor, unsigned* __restrict__ pairs, int E, int NB)
{
    __shared__ int hist[1024];
    __shared__ int base[1024];
    const int b0 = blockIdx.x * CHUNK;
    const int cnt = min(CHUNK, E - b0);
    const int tid = threadIdx.x;

    for (int i = tid; i < NB; i += 256) hist[i] = 0;
    __syncthreads();
    for (int i = tid; i < cnt; i += 256)
        atomicAdd(&hist[dst[b0 + i] >> 7], 1);
    __syncthreads();
    for (int i = tid; i < NB; i += 256) {
        const int c = hist[i];
        base[i] = c ? atomicAdd(&bcursor[i], c) : 0;
    }
    __syncthreads();
    int i = tid;
    for (; i + 768 < cnt; i += 1024) {
        const int d0 = dst[b0 + i], s0 = src[b0 + i];
        const int d1 = dst[b0 + i + 256], s1 = src[b0 + i + 256];
        const int d2 = dst[b0 + i + 512], s2 = src[b0 + i + 512];
        const int d3 = dst[b0 + i + 768], s3 = src[b0 + i + 768];
        const int p0 = atomicAdd(&base[d0 >> 7], 1);
        const int p1 = atomicAdd(&base[d1 >> 7], 1);
        const int p2 = atomicAdd(&base[d2 >> 7], 1);
        const int p3 = atomicAdd(&base[d3 >> 7], 1);
        pairs[p0] = (unsigned)s0 | ((unsigned)(d0 & 127) << 17);
        pairs[p1] = (unsigned)s1 | ((unsigned)(d1 & 127) << 17);
        pairs[p2] = (unsigned)s2 | ((unsigned)(d2 & 127) << 17);
        pairs[p3] = (unsigned)s3 | ((unsigned)(d3 & 127) << 17);
    }
    for (; i < cnt; i += 256) {
        const int d = dst[b0 + i];
        const int p = atomicAdd(&base[d >> 7], 1);
        pairs[p] = (unsigned)src[b0 + i] | ((unsigned)(d & 127) << 17);
    }
}

// One block per bucket: LDS counting sort of the bucket's pairs by local node.
__global__ __launch_bounds__(256) void k_sort(
    const unsigned* __restrict__ pairs, const int* __restrict__ bstart,
    int* __restrict__ edge_src, int* __restrict__ row_start, int N, int E)
{
    __shared__ unsigned sp[CAP];
    __shared__ int sorted[CAP];
    __shared__ int lcnt[128];
    __shared__ int ls[128];
    const int b = blockIdx.x;
    const int tid = threadIdx.x;
    const int beg = bstart[b], end = bstart[b + 1];
    const int cnt = end - beg;
    const bool fits = (cnt <= CAP);

    if (tid < 128) lcnt[tid] = 0;
    __syncthreads();

    if (fits) {
        for (int i = tid; i < cnt; i += 256) {
            const unsigned p = pairs[beg + i];
            sp[i] = p;
            atomicAdd(&lcnt[p >> 17], 1);
        }
    } else {
        for (int i = tid; i < cnt; i += 256)
            atomicAdd(&lcnt[pairs[beg + i] >> 17], 1);
    }
    __syncthreads();

    if (tid < 128) ls[tid] = lcnt[tid];
    __syncthreads();
    for (int off = 1; off < 128; off <<= 1) {
        int v = 0;
        if (tid < 128 && tid >= off) v = ls[tid - off];
        __syncthreads();
        if (tid < 128 && tid >= off) ls[tid] += v;
        __syncthreads();
    }

    if (tid < 128) {
        const int node = b * 128 + tid;
        if (node <= N) row_start[node] = beg + ls[tid] - lcnt[tid];
    }
    if (b == 0 && tid == 0) row_start[N] = E;
    __syncthreads();

    if (tid < 128) ls[tid] -= lcnt[tid];
    __syncthreads();

    if (fits) {
        for (int i = tid; i < cnt; i += 256) {
            const unsigned p = sp[i];
            const int pos = atomicAdd(&ls[p >> 17], 1);
            sorted[pos] = (int)(p & 0x1FFFFu);
        }
        __syncthreads();
        for (int i = tid; i < cnt; i += 256) edge_src[beg + i] = sorted[i];
    } else {
        for (int i = tid; i < cnt; i += 256) {
            const unsigned p = pairs[beg + i];
            const int pos = atomicAdd(&ls[p >> 17], 1);
            edge_src[beg + pos] = (int)(p & 0x1FFFFu);
        }
    }
}

// One wave per node: acc = (1/deg) * sum_{j in [beg,end)} M[edge_src[j]]  (+bias)
template<int C, bool ADDBIAS>
__global__ __launch_bounds__(256) void k_agg(
    const float* __restrict__ M, const int* __restrict__ edge_src,
    const int* __restrict__ row_start, const float* __restrict__ bias,
    float* __restrict__ outp, int N)
{
    const int w = (blockIdx.x * 256 + threadIdx.x) >> 6;
    if (w >= N) return;
    const int lane = threadIdx.x & 63;
    const int beg = row_start[w];
    const int end = row_start[w + 1];
    const float inv = 1.0f / fmaxf((float)(end - beg), 1.0f);

    if (C == 128) {
        const int c = lane * 2;
        float ax = 0.f, ay = 0.f, bx = 0.f, by = 0.f;
        int j = beg;
        for (; j + 3 < end; j += 4) {
            const int s0 = edge_src[j + 0], s1 = edge_src[j + 1];
            const int s2 = edge_src[j + 2], s3 = edge_src[j + 3];
            const float2 v0 = *(const float2*)(M + (size_t)s0 * 128 + c);
            const float2 v1 = *(const float2*)(M + (size_t)s1 * 128 + c);
            const float2 v2 = *(const float2*)(M + (size_t)s2 * 128 + c);
            const float2 v3 = *(const float2*)(M + (size_t)s3 * 128 + c);
            ax += v0.x + v2.x; ay += v0.y + v2.y;
            bx += v1.x + v3.x; by += v1.y + v3.y;
        }
        for (; j < end; ++j) {
            const float2 v = *(const float2*)(M + (size_t)edge_src[j] * 128 + c);
            ax += v.x; ay += v.y;
        }
        float2 o;
        o.x = (ax + bx) * inv;
        o.y = (ay + by) * inv;
        *(float2*)(outp + (size_t)w * 128 + c) = o;
    } else {
        float a = 0.f, b = 0.f, cc = 0.f, d = 0.f;
        int j = beg;
        for (; j + 3 < end; j += 4) {
            a  += M[(size_t)edge_src[j + 0] * 64 + lane];
            b  += M[(size_t)edge_src[j + 1] * 64 + lane];
            cc += M[(size_t)edge_src[j + 2] * 64 + lane];
            d  += M[(size_t)edge_src[j + 3] * 64 + lane];
        }
        for (; j < end; ++j) a += M[(size_t)edge_src[j] * 64 + lane];
        float o = (a + b + cc + d) * inv;
        if (ADDBIAS) o += bias[lane];
        outp[(size_t)w * 64 + lane] = o;
    }
}

// C[row, 0:OUTC] = A[row, 0:128] @ W[128, OUTC] (+ bias&relu). 64 rows/block,
// 256 threads, A tile in LDS. In-place safe (full tile staged before writes).
template<int OUTC, bool BIASRELU>
__global__ __launch_bounds__(256) void k_gemm(
    const float* __restrict__ A, const float* __restrict__ W,
    const float* __restrict__ bias, float* __restrict__ C, int N, int out_stride)
{
    __shared__ float As[64][128];
    const int tid = threadIdx.x;
    const int row0 = blockIdx.x * 64;

    for (int i = tid; i < 64 * 32; i += 256) {
        const int r = i >> 5;
        const int cc = (i & 31) << 2;
        const int row = row0 + r;
        float4 v = make_float4(0.f, 0.f, 0.f, 0.f);
        if (row < N) v = *(const float4*)(A + (size_t)row * 128 + cc);
        *(float4*)&As[r][cc] = v;
    }
    __syncthreads();

    constexpr int CG = OUTC / 4;
    constexpr int RPT = (64 * CG) / 256;
    const int cg = tid & (CG - 1);
    const int rg = tid / CG;
    const int c0 = cg * 4;
    const int r0 = rg * RPT;

    float acc[RPT][4];
#pragma unroll
    for (int r = 0; r < RPT; ++r)
        for (int j = 0; j < 4; ++j) acc[r][j] = 0.f;

#pragma unroll 2
    for (int k = 0; k < 128; k += 4) {
        const float4 w0 = *(const float4*)(W + (size_t)(k + 0) * OUTC + c0);
        const float4 w1 = *(const float4*)(W + (size_t)(k + 1) * OUTC + c0);
        const float4 w2 = *(const float4*)(W + (size_t)(k + 2) * OUTC + c0);
        const float4 w3 = *(const float4*)(W + (size_t)(k + 3) * OUTC + c0);
#pragma unroll
        for (int r = 0; r < RPT; ++r) {
            const float4 a = *(const float4*)&As[r0 + r][k];
            acc[r][0] = fmaf(a.x, w0.x, fmaf(a.y, w1.x, fmaf(a.z, w2.x, fmaf(a.w, w3.x, acc[r][0]))));
            acc[r][1] = fmaf(a.x, w0.y, fmaf(a.y, w1.y, fmaf(a.z, w2.y, fmaf(a.w, w3.y, acc[r][1]))));
            acc[r][2] = fmaf(a.x, w0.z, fmaf(a.y, w1.z, fmaf(a.z, w2.z, fmaf(a.w, w3.z, acc[r][2]))));
            acc[r][3] = fmaf(a.x, w0.w, fmaf(a.y, w1.w, fmaf(a.z, w2.w, fmaf(a.w, w3.w, acc[r][3]))));
        }
    }

#pragma unroll
    for (int r = 0; r < RPT; ++r) {
        const int row = row0 + r0 + r;
        if (row >= N) continue;
        float4 o = make_float4(acc[r][0], acc[r][1], acc[r][2], acc[r][3]);
        if (BIASRELU) {
            const float4 b = *(const float4*)(bias + c0);
            o.x = fmaxf(o.x + b.x, 0.f);
            o.y = fmaxf(o.y + b.y, 0.f);
            o.z = fmaxf(o.z + b.z, 0.f);
            o.w = fmaxf(o.w + b.w, 0.f);
        }
        *(float4*)(C + (size_t)row * out_stride + c0) = o;
    }
}

extern "C" void kernel_launch(void* const* d_in, const int* in_sizes, int n_in,
                              void* d_out, int out_size, void* d_ws, size_t ws_size,
                              hipStream_t stream)
{
    const float* X  = (const float*)d_in[0];
    const int*  src = (const int*)d_in[1];
    const int*  dst = (const int*)d_in[2];
    const float* W1 = (const float*)d_in[3];
    const float* b1 = (const float*)d_in[4];
    const float* W2 = (const float*)d_in[5];
    const float* b2 = (const float*)d_in[6];
    float* out = (float*)d_out;

    const int N = in_sizes[0] / 128;
    const int E = in_sizes[1];
    const int NB = (N + 127) / 128;

    float* buf1 = (float*)d_ws;                          // N*128: agg1 -> h
    unsigned* pairs = (unsigned*)buf1;                   // aliases buf1 (dead before agg1)
    float* m2       = buf1 + (size_t)N * 128;            // N*64
    int* edge_src   = (int*)(m2 + (size_t)N * 64);       // E
    int* row_start  = edge_src + E;                      // N+1
    int* bcnt       = row_start + N + 1;                 // NB
    int* bstart     = bcnt + NB;                         // NB+1
    int* bcursor    = bstart + NB + 1;                   // NB

    hipMemsetAsync(bcnt, 0, (size_t)NB * sizeof(int), stream);

    // --- CSR build: bucket hist -> scan -> reserved binscatter -> LDS sort ---
    k_bhist<<<256, 256, 0, stream>>>(dst, bcnt, E, NB);
    k_bscan<<<1, 1024, 0, stream>>>(bcnt, bstart, bcursor, NB, E);
    k_binscatter<<<(E + CHUNK - 1) / CHUNK, 256, 0, stream>>>(src, dst, bcursor, pairs, E, NB);
    k_sort<<<NB, 256, 0, stream>>>(pairs, bstart, edge_src, row_start, N, E);

    // --- layer 1: gather-agg (scaled), then GEMM+bias+relu ---
    k_agg<128, false><<<(N + 3) / 4, 256, 0, stream>>>(X, edge_src, row_start, nullptr, buf1, N);
    k_gemm<128, true><<<(N + 63) / 64, 256, 0, stream>>>(buf1, W1, b1, buf1, N, 128);

    // --- layer 2: GEMM, then gather-agg with fused (1/deg, +b2) epilogue ---
    k_gemm<64, false><<<(N + 63) / 64, 256, 0, stream>>>(buf1, W2, nullptr, m2, N, 64);
    k_agg<64, true><<<(N + 3) / 4, 256, 0, stream>>>(m2, edge_src, row_start, b2, out, N);
}

// Round 6
// 295.051 us; speedup vs baseline: 8.1905x; 1.1431x over previous
//
#include <hip/hip_runtime.h>
#include <hip/hip_fp16.h>

// GCN via two-level CSR build + wave-per-node gather aggregation, fp16 payloads:
//   1) k_bhist/k_bscan: bucket histogram + scan (bucket = dst>>7, 128 nodes)
//   2) k_binscatter: LDS hist -> bulk cursor reservation -> low-contention scatter
//   3) k_sort: per-bucket LDS counting sort -> edge_src (dst-sorted), row_start
//   4) X16 = fp16(X);  agg1[n] = (1/deg) * sum X16[src]   (wave/node, f32 acc)
//   5) h  = relu(agg1 @ W1 + b1)                          (fp32 GEMM)
//   6) m2h = fp16(h @ W2)
//   7) out[n] = (1/deg) * sum m2h[src] + b2               (2 edges/wave, f32 acc)
// Requires N <= 2^17. N = 100000 here.

constexpr int CAP = 6144;
constexpr int CHUNK = 8192;

__global__ __launch_bounds__(256) void k_bhist(
    const int* __restrict__ dst, int* __restrict__ bcnt, int E, int NB)
{
    __shared__ int sh[1024];
    for (int i = threadIdx.x; i < NB; i += 256) sh[i] = 0;
    __syncthreads();
    for (int e = blockIdx.x * 256 + threadIdx.x; e < E; e += gridDim.x * 256)
        atomicAdd(&sh[dst[e] >> 7], 1);
    __syncthreads();
    for (int i = threadIdx.x; i < NB; i += 256) {
        const int v = sh[i];
        if (v) atomicAdd(&bcnt[i], v);
    }
}

__global__ __launch_bounds__(1024) void k_bscan(
    const int* __restrict__ bcnt, int* __restrict__ bstart,
    int* __restrict__ bcursor, int NB, int E)
{
    __shared__ int sh[1024];
    const int t = threadIdx.x;
    const int v = (t < NB) ? bcnt[t] : 0;
    sh[t] = v;
    __syncthreads();
    for (int off = 1; off < 1024; off <<= 1) {
        int u = (t >= off) ? sh[t - off] : 0;
        __syncthreads();
        if (t >= off) sh[t] += u;
        __syncthreads();
    }
    if (t < NB) {
        const int ex = sh[t] - v;
        bstart[t] = ex;
        bcursor[t] = ex;
    }
    if (t == 0) bstart[NB] = E;
}

__global__ __launch_bounds__(256) void k_binscatter(
    const int* __restrict__ src, const int* __restrict__ dst,
    int* __restrict__ bcursor, unsigned* __restrict__ pairs, int E, int NB)
{
    __shared__ int hist[1024];
    __shared__ int base[1024];
    const int b0 = blockIdx.x * CHUNK;
    const int cnt = min(CHUNK, E - b0);
    const int tid = threadIdx.x;

    for (int i = tid; i < NB; i += 256) hist[i] = 0;
    __syncthreads();
    for (int i = tid; i < cnt; i += 256)
        atomicAdd(&hist[dst[b0 + i] >> 7], 1);
    __syncthreads();
    for (int i = tid; i < NB; i += 256) {
        const int c = hist[i];
        base[i] = c ? atomicAdd(&bcursor[i], c) : 0;
    }
    __syncthreads();
    int i = tid;
    for (; i + 768 < cnt; i += 1024) {
        const int d0 = dst[b0 + i], s0 = src[b0 + i];
        const int d1 = dst[b0 + i + 256], s1 = src[b0 + i + 256];
        const int d2 = dst[b0 + i + 512], s2 = src[b0 + i + 512];
        const int d3 = dst[b0 + i + 768], s3 = src[b0 + i + 768];
        const int p0 = atomicAdd(&base[d0 >> 7], 1);
        const int p1 = atomicAdd(&base[d1 >> 7], 1);
        const int p2 = atomicAdd(&base[d2 >> 7], 1);
        const int p3 = atomicAdd(&base[d3 >> 7], 1);
        pairs[p0] = (unsigned)s0 | ((unsigned)(d0 & 127) << 17);
        pairs[p1] = (unsigned)s1 | ((unsigned)(d1 & 127) << 17);
        pairs[p2] = (unsigned)s2 | ((unsigned)(d2 & 127) << 17);
        pairs[p3] = (unsigned)s3 | ((unsigned)(d3 & 127) << 17);
    }
    for (; i < cnt; i += 256) {
        const int d = dst[b0 + i];
        const int p = atomicAdd(&base[d >> 7], 1);
        pairs[p] = (unsigned)src[b0 + i] | ((unsigned)(d & 127) << 17);
    }
}

__global__ __launch_bounds__(256) void k_sort(
    const unsigned* __restrict__ pairs, const int* __restrict__ bstart,
    int* __restrict__ edge_src, int* __restrict__ row_start, int N, int E)
{
    __shared__ unsigned sp[CAP];
    __shared__ int sorted[CAP];
    __shared__ int lcnt[128];
    __shared__ int ls[128];
    const int b = blockIdx.x;
    const int tid = threadIdx.x;
    const int beg = bstart[b], end = bstart[b + 1];
    const int cnt = end - beg;
    const bool fits = (cnt <= CAP);

    if (tid < 128) lcnt[tid] = 0;
    __syncthreads();

    if (fits) {
        for (int i = tid; i < cnt; i += 256) {
            const unsigned p = pairs[beg + i];
            sp[i] = p;
            atomicAdd(&lcnt[p >> 17], 1);
        }
    } else {
        for (int i = tid; i < cnt; i += 256)
            atomicAdd(&lcnt[pairs[beg + i] >> 17], 1);
    }
    __syncthreads();

    if (tid < 128) ls[tid] = lcnt[tid];
    __syncthreads();
    for (int off = 1; off < 128; off <<= 1) {
        int v = 0;
        if (tid < 128 && tid >= off) v = ls[tid - off];
        __syncthreads();
        if (tid < 128 && tid >= off) ls[tid] += v;
        __syncthreads();
    }

    if (tid < 128) {
        const int node = b * 128 + tid;
        if (node <= N) row_start[node] = beg + ls[tid] - lcnt[tid];
    }
    if (b == 0 && tid == 0) row_start[N] = E;
    __syncthreads();

    if (tid < 128) ls[tid] -= lcnt[tid];
    __syncthreads();

    if (fits) {
        for (int i = tid; i < cnt; i += 256) {
            const unsigned p = sp[i];
            const int pos = atomicAdd(&ls[p >> 17], 1);
            sorted[pos] = (int)(p & 0x1FFFFu);
        }
        __syncthreads();
        for (int i = tid; i < cnt; i += 256) edge_src[beg + i] = sorted[i];
    } else {
        for (int i = tid; i < cnt; i += 256) {
            const unsigned p = pairs[beg + i];
            const int pos = atomicAdd(&ls[p >> 17], 1);
            edge_src[beg + pos] = (int)(p & 0x1FFFFu);
        }
    }
}

// fp32 -> fp16 convert, 4 elems/thread.
__global__ __launch_bounds__(256) void k_cvt(
    const float* __restrict__ in, __half* __restrict__ outp, long long n4)
{
    const long long i = (long long)blockIdx.x * 256 + threadIdx.x;
    if (i >= n4) return;
    const float4 v = ((const float4*)in)[i];
    __half2 h0 = __floats2half2_rn(v.x, v.y);
    __half2 h1 = __floats2half2_rn(v.z, v.w);
    uint2 o;
    o.x = *(const unsigned*)&h0;
    o.y = *(const unsigned*)&h1;
    ((uint2*)outp)[i] = o;
}

// Layer-1 agg: wave per node, gather fp16 rows (128 ch), fp32 accumulate,
// apply 1/deg, write fp32.
__global__ __launch_bounds__(256) void k_agg128h(
    const __half* __restrict__ M, const int* __restrict__ edge_src,
    const int* __restrict__ row_start, float* __restrict__ outp, int N)
{
    const int w = (blockIdx.x * 256 + threadIdx.x) >> 6;
    if (w >= N) return;
    const int lane = threadIdx.x & 63;
    const int beg = row_start[w];
    const int end = row_start[w + 1];
    const float inv = 1.0f / fmaxf((float)(end - beg), 1.0f);
    const __half2* M2 = (const __half2*)M;   // 64 half2 per row

    float ax = 0.f, ay = 0.f, bx = 0.f, by = 0.f;
    int j = beg;
    for (; j + 3 < end; j += 4) {
        const int s0 = edge_src[j + 0], s1 = edge_src[j + 1];
        const int s2 = edge_src[j + 2], s3 = edge_src[j + 3];
        const float2 v0 = __half22float2(M2[(size_t)s0 * 64 + lane]);
        const float2 v1 = __half22float2(M2[(size_t)s1 * 64 + lane]);
        const float2 v2 = __half22float2(M2[(size_t)s2 * 64 + lane]);
        const float2 v3 = __half22float2(M2[(size_t)s3 * 64 + lane]);
        ax += v0.x + v2.x; ay += v0.y + v2.y;
        bx += v1.x + v3.x; by += v1.y + v3.y;
    }
    for (; j < end; ++j) {
        const float2 v = __half22float2(M2[(size_t)edge_src[j] * 64 + lane]);
        ax += v.x; ay += v.y;
    }
    float2 o;
    o.x = (ax + bx) * inv;
    o.y = (ay + by) * inv;
    ((float2*)(outp + (size_t)w * 128))[lane] = o;
}

// Layer-2 agg: wave per node, 2 edges in flight (half-wave each), fp16 rows
// (64 ch = 32 half2), fp32 acc, combine via shfl_xor(32), epi = *inv + b2.
__global__ __launch_bounds__(256) void k_agg64h(
    const __half* __restrict__ M, const int* __restrict__ edge_src,
    const int* __restrict__ row_start, const float* __restrict__ bias,
    float* __restrict__ outp, int N)
{
    const int w = (blockIdx.x * 256 + threadIdx.x) >> 6;
    if (w >= N) return;
    const int lane = threadIdx.x & 63;
    const int half = lane >> 5;
    const int l = lane & 31;
    const int beg = row_start[w];
    const int end = row_start[w + 1];
    const float inv = 1.0f / fmaxf((float)(end - beg), 1.0f);
    const __half2* M2 = (const __half2*)M;   // 32 half2 per row

    float ax = 0.f, ay = 0.f, bx = 0.f, by = 0.f;
    int j = beg + half;
    for (; j + 2 < end; j += 4) {
        const int s0 = edge_src[j];
        const int s1 = edge_src[j + 2];
        const float2 v0 = __half22float2(M2[(size_t)s0 * 32 + l]);
        const float2 v1 = __half22float2(M2[(size_t)s1 * 32 + l]);
        ax += v0.x; ay += v0.y;
        bx += v1.x; by += v1.y;
    }
    for (; j < end; j += 2) {
        const float2 v = __half22float2(M2[(size_t)edge_src[j] * 32 + l]);
        ax += v.x; ay += v.y;
    }
    ax += bx; ay += by;
    ax += __shfl_xor(ax, 32);
    ay += __shfl_xor(ay, 32);
    if (half == 0) {
        const float2 b = ((const float2*)bias)[l];
        float2 o;
        o.x = fmaf(ax, inv, b.x);
        o.y = fmaf(ay, inv, b.y);
        ((float2*)(outp + (size_t)w * 64))[l] = o;
    }
}

// C[row,0:OUTC] = A[row,0:128] @ W[128,OUTC] (+bias&relu). HALFOUT: C is __half*.
template<int OUTC, bool BIASRELU, bool HALFOUT>
__global__ __launch_bounds__(256) void k_gemm(
    const float* __restrict__ A, const float* __restrict__ W,
    const float* __restrict__ bias, void* __restrict__ Cp, int N, int out_stride)
{
    __shared__ float As[64][128];
    const int tid = threadIdx.x;
    const int row0 = blockIdx.x * 64;

    for (int i = tid; i < 64 * 32; i += 256) {
        const int r = i >> 5;
        const int cc = (i & 31) << 2;
        const int row = row0 + r;
        float4 v = make_float4(0.f, 0.f, 0.f, 0.f);
        if (row < N) v = *(const float4*)(A + (size_t)row * 128 + cc);
        *(float4*)&As[r][cc] = v;
    }
    __syncthreads();

    constexpr int CG = OUTC / 4;
    constexpr int RPT = (64 * CG) / 256;
    const int cg = tid & (CG - 1);
    const int rg = tid / CG;
    const int c0 = cg * 4;
    const int r0 = rg * RPT;

    float acc[RPT][4];
#pragma unroll
    for (int r = 0; r < RPT; ++r)
        for (int j = 0; j < 4; ++j) acc[r][j] = 0.f;

#pragma unroll 2
    for (int k = 0; k < 128; k += 4) {
        const float4 w0 = *(const float4*)(W + (size_t)(k + 0) * OUTC + c0);
        const float4 w1 = *(const float4*)(W + (size_t)(k + 1) * OUTC + c0);
        const float4 w2 = *(const float4*)(W + (size_t)(k + 2) * OUTC + c0);
        const float4 w3 = *(const float4*)(W + (size_t)(k + 3) * OUTC + c0);
#pragma unroll
        for (int r = 0; r < RPT; ++r) {
            const float4 a = *(const float4*)&As[r0 + r][k];
            acc[r][0] = fmaf(a.x, w0.x, fmaf(a.y, w1.x, fmaf(a.z, w2.x, fmaf(a.w, w3.x, acc[r][0]))));
            acc[r][1] = fmaf(a.x, w0.y, fmaf(a.y, w1.y, fmaf(a.z, w2.y, fmaf(a.w, w3.y, acc[r][1]))));
            acc[r][2] = fmaf(a.x, w0.z, fmaf(a.y, w1.z, fmaf(a.z, w2.z, fmaf(a.w, w3.z, acc[r][2]))));
            acc[r][3] = fmaf(a.x, w0.w, fmaf(a.y, w1.w, fmaf(a.z, w2.w, fmaf(a.w, w3.w, acc[r][3]))));
        }
    }

#pragma unroll
    for (int r = 0; r < RPT; ++r) {
        const int row = row0 + r0 + r;
        if (row >= N) continue;
        float4 o = make_float4(acc[r][0], acc[r][1], acc[r][2], acc[r][3]);
        if (BIASRELU) {
            const float4 b = *(const float4*)(bias + c0);
            o.x = fmaxf(o.x + b.x, 0.f);
            o.y = fmaxf(o.y + b.y, 0.f);
            o.z = fmaxf(o.z + b.z, 0.f);
            o.w = fmaxf(o.w + b.w, 0.f);
        }
        if (HALFOUT) {
            __half2 h0 = __floats2half2_rn(o.x, o.y);
            __half2 h1 = __floats2half2_rn(o.z, o.w);
            uint2 u;
            u.x = *(const unsigned*)&h0;
            u.y = *(const unsigned*)&h1;
            *(uint2*)((__half*)Cp + (size_t)row * out_stride + c0) = u;
        } else {
            *(float4*)((float*)Cp + (size_t)row * out_stride + c0) = o;
        }
    }
}

extern "C" void kernel_launch(void* const* d_in, const int* in_sizes, int n_in,
                              void* d_out, int out_size, void* d_ws, size_t ws_size,
                              hipStream_t stream)
{
    const float* X  = (const float*)d_in[0];
    const int*  src = (const int*)d_in[1];
    const int*  dst = (const int*)d_in[2];
    const float* W1 = (const float*)d_in[3];
    const float* b1 = (const float*)d_in[4];
    const float* W2 = (const float*)d_in[5];
    const float* b2 = (const float*)d_in[6];
    float* out = (float*)d_out;

    const int N = in_sizes[0] / 128;
    const int E = in_sizes[1];
    const int NB = (N + 127) / 128;

    float* buf1 = (float*)d_ws;                          // N*128 f32: agg1 -> h
    unsigned* pairs = (unsigned*)buf1;                   // aliases buf1 (dead before agg1)
    __half* X16     = (__half*)(buf1 + (size_t)N * 128); // N*128 f16
    __half* m2h     = X16 + (size_t)N * 128;             // N*64 f16
    int* edge_src   = (int*)(m2h + (size_t)N * 64);      // E
    int* row_start  = edge_src + E;                      // N+1
    int* bcnt       = row_start + N + 1;                 // NB
    int* bstart     = bcnt + NB;                         // NB+1
    int* bcursor    = bstart + NB + 1;                   // NB

    hipMemsetAsync(bcnt, 0, (size_t)NB * sizeof(int), stream);

    // --- CSR build + X conversion (independent, overlappable) ---
    k_bhist<<<256, 256, 0, stream>>>(dst, bcnt, E, NB);
    k_cvt<<<(int)(((long long)N * 32 + 255) / 256), 256, 0, stream>>>(X, X16, (long long)N * 32);
    k_bscan<<<1, 1024, 0, stream>>>(bcnt, bstart, bcursor, NB, E);
    k_binscatter<<<(E + CHUNK - 1) / CHUNK, 256, 0, stream>>>(src, dst, bcursor, pairs, E, NB);
    k_sort<<<NB, 256, 0, stream>>>(pairs, bstart, edge_src, row_start, N, E);

    // --- layer 1: fp16 gather-agg, then fp32 GEMM+bias+relu ---
    k_agg128h<<<(N + 3) / 4, 256, 0, stream>>>(X16, edge_src, row_start, buf1, N);
    k_gemm<128, true, false><<<(N + 63) / 64, 256, 0, stream>>>(buf1, W1, b1, buf1, N, 128);

    // --- layer 2: GEMM -> fp16 m2, then fp16 gather-agg with fused epilogue ---
    k_gemm<64, false, true><<<(N + 63) / 64, 256, 0, stream>>>(buf1, W2, nullptr, m2h, N, 64);
    k_agg64h<<<(N + 3) / 4, 256, 0, stream>>>(m2h, edge_src, row_start, b2, out, N);
}

// Round 7
// 268.597 us; speedup vs baseline: 8.9971x; 1.0985x over previous
//
#include <hip/hip_runtime.h>
#include <hip/hip_fp16.h>

// GCN: two-level CSR build + wave-per-node fp16 gather agg + fp16 MFMA GEMMs.
//   1) k_bhist_cvt: bucket hist (dst>>7) + fused X->fp16 convert
//   2) k_bscan: bucket exclusive scan
//   3) k_binscatter: LDS hist -> bulk cursor reservation -> low-contention scatter
//   4) k_sort: per-bucket LDS counting sort -> edge_src (dst-sorted), row_start
//   5) k_agg128h: agg1h[n] = fp16( (1/deg) * sum X16[src] )   (f32 acc)
//   6) k_mgemm<128>: h = fp16(relu(agg1h @ W1 + b1))          (mfma 16x16x32 f16)
//   7) k_mgemm<64>:  m2h = fp16(h @ W2)
//   8) k_agg64h: out[n] = (1/deg) * sum m2h[src] + b2         (f32 out)
// Requires N <= 2^17. N = 100000 here.

constexpr int CAP = 6144;
constexpr int CHUNK = 8192;

typedef _Float16 f16x8 __attribute__((ext_vector_type(8)));
typedef float f32x4 __attribute__((ext_vector_type(4)));

__global__ __launch_bounds__(256) void k_bhist_cvt(
    const int* __restrict__ dst, int* __restrict__ bcnt,
    const float* __restrict__ X, __half* __restrict__ X16,
    int E, int NB, long long n4)
{
    __shared__ int sh[1024];
    for (int i = threadIdx.x; i < NB; i += 256) sh[i] = 0;
    __syncthreads();
    for (int e = blockIdx.x * 256 + threadIdx.x; e < E; e += gridDim.x * 256)
        atomicAdd(&sh[dst[e] >> 7], 1);
    __syncthreads();
    for (int i = threadIdx.x; i < NB; i += 256) {
        const int v = sh[i];
        if (v) atomicAdd(&bcnt[i], v);
    }
    for (long long i = (long long)blockIdx.x * 256 + threadIdx.x; i < n4;
         i += (long long)gridDim.x * 256) {
        const float4 v = ((const float4*)X)[i];
        __half2 h0 = __floats2half2_rn(v.x, v.y);
        __half2 h1 = __floats2half2_rn(v.z, v.w);
        uint2 o;
        o.x = *(const unsigned*)&h0;
        o.y = *(const unsigned*)&h1;
        ((uint2*)X16)[i] = o;
    }
}

// W1 [128x128] f32 -> W1t [n][k] f16 ; W2 [128x64] f32 -> W2t [n][k] f16
__global__ __launch_bounds__(256) void k_cvtW(
    const float* __restrict__ W1, const float* __restrict__ W2,
    __half* __restrict__ W1t, __half* __restrict__ W2t)
{
    const int t = blockIdx.x * 256 + threadIdx.x;
    if (t < 128 * 128) {
        const int k = t >> 7, n = t & 127;
        W1t[n * 128 + k] = __float2half(W1[t]);
    } else {
        const int u = t - 128 * 128;
        if (u < 128 * 64) {
            const int k = u >> 6, n = u & 63;
            W2t[n * 128 + k] = __float2half(W2[u]);
        }
    }
}

__global__ __launch_bounds__(1024) void k_bscan(
    const int* __restrict__ bcnt, int* __restrict__ bstart,
    int* __restrict__ bcursor, int NB, int E)
{
    __shared__ int sh[1024];
    const int t = threadIdx.x;
    const int v = (t < NB) ? bcnt[t] : 0;
    sh[t] = v;
    __syncthreads();
    for (int off = 1; off < 1024; off <<= 1) {
        int u = (t >= off) ? sh[t - off] : 0;
        __syncthreads();
        if (t >= off) sh[t] += u;
        __syncthreads();
    }
    if (t < NB) {
        const int ex = sh[t] - v;
        bstart[t] = ex;
        bcursor[t] = ex;
    }
    if (t == 0) bstart[NB] = E;
}

__global__ __launch_bounds__(256) void k_binscatter(
    const int* __restrict__ src, const int* __restrict__ dst,
    int* __restrict__ bcursor, unsigned* __restrict__ pairs, int E, int NB)
{
    __shared__ int hist[1024];
    __shared__ int base[1024];
    const int b0 = blockIdx.x * CHUNK;
    const int cnt = min(CHUNK, E - b0);
    const int tid = threadIdx.x;

    for (int i = tid; i < NB; i += 256) hist[i] = 0;
    __syncthreads();
    for (int i = tid; i < cnt; i += 256)
        atomicAdd(&hist[dst[b0 + i] >> 7], 1);
    __syncthreads();
    for (int i = tid; i < NB; i += 256) {
        const int c = hist[i];
        base[i] = c ? atomicAdd(&bcursor[i], c) : 0;
    }
    __syncthreads();
    int i = tid;
    for (; i + 768 < cnt; i += 1024) {
        const int d0 = dst[b0 + i], s0 = src[b0 + i];
        const int d1 = dst[b0 + i + 256], s1 = src[b0 + i + 256];
        const int d2 = dst[b0 + i + 512], s2 = src[b0 + i + 512];
        const int d3 = dst[b0 + i + 768], s3 = src[b0 + i + 768];
        const int p0 = atomicAdd(&base[d0 >> 7], 1);
        const int p1 = atomicAdd(&base[d1 >> 7], 1);
        const int p2 = atomicAdd(&base[d2 >> 7], 1);
        const int p3 = atomicAdd(&base[d3 >> 7], 1);
        pairs[p0] = (unsigned)s0 | ((unsigned)(d0 & 127) << 17);
        pairs[p1] = (unsigned)s1 | ((unsigned)(d1 & 127) << 17);
        pairs[p2] = (unsigned)s2 | ((unsigned)(d2 & 127) << 17);
        pairs[p3] = (unsigned)s3 | ((unsigned)(d3 & 127) << 17);
    }
    for (; i < cnt; i += 256) {
        const int d = dst[b0 + i];
        const int p = atomicAdd(&base[d >> 7], 1);
        pairs[p] = (unsigned)src[b0 + i] | ((unsigned)(d & 127) << 17);
    }
}

__global__ __launch_bounds__(256) void k_sort(
    const unsigned* __restrict__ pairs, const int* __restrict__ bstart,
    int* __restrict__ edge_src, int* __restrict__ row_start, int N, int E)
{
    __shared__ unsigned sp[CAP];
    __shared__ int sorted[CAP];
    __shared__ int lcnt[128];
    __shared__ int ls[128];
    const int b = blockIdx.x;
    const int tid = threadIdx.x;
    const int beg = bstart[b], end = bstart[b + 1];
    const int cnt = end - beg;
    const bool fits = (cnt <= CAP);

    if (tid < 128) lcnt[tid] = 0;
    __syncthreads();

    if (fits) {
        for (int i = tid; i < cnt; i += 256) {
            const unsigned p = pairs[beg + i];
            sp[i] = p;
            atomicAdd(&lcnt[p >> 17], 1);
        }
    } else {
        for (int i = tid; i < cnt; i += 256)
            atomicAdd(&lcnt[pairs[beg + i] >> 17], 1);
    }
    __syncthreads();

    if (tid < 128) ls[tid] = lcnt[tid];
    __syncthreads();
    for (int off = 1; off < 128; off <<= 1) {
        int v = 0;
        if (tid < 128 && tid >= off) v = ls[tid - off];
        __syncthreads();
        if (tid < 128 && tid >= off) ls[tid] += v;
        __syncthreads();
    }

    if (tid < 128) {
        const int node = b * 128 + tid;
        if (node <= N) row_start[node] = beg + ls[tid] - lcnt[tid];
    }
    if (b == 0 && tid == 0) row_start[N] = E;
    __syncthreads();

    if (tid < 128) ls[tid] -= lcnt[tid];
    __syncthreads();

    if (fits) {
        for (int i = tid; i < cnt; i += 256) {
            const unsigned p = sp[i];
            const int pos = atomicAdd(&ls[p >> 17], 1);
            sorted[pos] = (int)(p & 0x1FFFFu);
        }
        __syncthreads();
        for (int i = tid; i < cnt; i += 256) edge_src[beg + i] = sorted[i];
    } else {
        for (int i = tid; i < cnt; i += 256) {
            const unsigned p = pairs[beg + i];
            const int pos = atomicAdd(&ls[p >> 17], 1);
            edge_src[beg + pos] = (int)(p & 0x1FFFFu);
        }
    }
}

// Layer-1 agg: wave per node, fp16 gather (128 ch), f32 acc, fp16 out w/ 1/deg.
__global__ __launch_bounds__(256) void k_agg128h(
    const __half* __restrict__ M, const int* __restrict__ edge_src,
    const int* __restrict__ row_start, __half* __restrict__ outp, int N)
{
    const int w = (blockIdx.x * 256 + threadIdx.x) >> 6;
    if (w >= N) return;
    const int lane = threadIdx.x & 63;
    const int beg = row_start[w];
    const int end = row_start[w + 1];
    const float inv = 1.0f / fmaxf((float)(end - beg), 1.0f);
    const __half2* M2 = (const __half2*)M;

    float ax = 0.f, ay = 0.f, bx = 0.f, by = 0.f;
    int j = beg;
    for (; j + 3 < end; j += 4) {
        const int s0 = edge_src[j + 0], s1 = edge_src[j + 1];
        const int s2 = edge_src[j + 2], s3 = edge_src[j + 3];
        const float2 v0 = __half22float2(M2[(size_t)s0 * 64 + lane]);
        const float2 v1 = __half22float2(M2[(size_t)s1 * 64 + lane]);
        const float2 v2 = __half22float2(M2[(size_t)s2 * 64 + lane]);
        const float2 v3 = __half22float2(M2[(size_t)s3 * 64 + lane]);
        ax += v0.x + v2.x; ay += v0.y + v2.y;
        bx += v1.x + v3.x; by += v1.y + v3.y;
    }
    for (; j < end; ++j) {
        const float2 v = __half22float2(M2[(size_t)edge_src[j] * 64 + lane]);
        ax += v.x; ay += v.y;
    }
    ((__half2*)(outp + (size_t)w * 128))[lane] =
        __floats2half2_rn((ax + bx) * inv, (ay + by) * inv);
}

// Layer-2 agg: wave per node, 2 edges in flight, fp16 rows (64 ch), f32 out.
__global__ __launch_bounds__(256) void k_agg64h(
    const __half* __restrict__ M, const int* __restrict__ edge_src,
    const int* __restrict__ row_start, const float* __restrict__ bias,
    float* __restrict__ outp, int N)
{
    const int w = (blockIdx.x * 256 + threadIdx.x) >> 6;
    if (w >= N) return;
    const int lane = threadIdx.x & 63;
    const int half = lane >> 5;
    const int l = lane & 31;
    const int beg = row_start[w];
    const int end = row_start[w + 1];
    const float inv = 1.0f / fmaxf((float)(end - beg), 1.0f);
    const __half2* M2 = (const __half2*)M;

    float ax = 0.f, ay = 0.f, bx = 0.f, by = 0.f;
    int j = beg + half;
    for (; j + 2 < end; j += 4) {
        const int s0 = edge_src[j];
        const int s1 = edge_src[j + 2];
        const float2 v0 = __half22float2(M2[(size_t)s0 * 32 + l]);
        const float2 v1 = __half22float2(M2[(size_t)s1 * 32 + l]);
        ax += v0.x; ay += v0.y;
        bx += v1.x; by += v1.y;
    }
    for (; j < end; j += 2) {
        const float2 v = __half22float2(M2[(size_t)edge_src[j] * 32 + l]);
        ax += v.x; ay += v.y;
    }
    ax += bx; ay += by;
    ax += __shfl_xor(ax, 32);
    ay += __shfl_xor(ay, 32);
    if (half == 0) {
        const float2 b = ((const float2*)bias)[l];
        float2 o;
        o.x = fmaf(ax, inv, b.x);
        o.y = fmaf(ay, inv, b.y);
        ((float2*)(outp + (size_t)w * 64))[l] = o;
    }
}

// MFMA fp16 GEMM: C[64 rows x NCOLS] = A[64x128] @ Wt^T (+bias, relu), fp16 out.
// A fp16 row-major; Wt fp16 [NCOLS][128] (pre-transposed). 256 thr = 4 waves,
// 16 rows/wave. LDS: swizzled A tile (16 KB), reused for epilogue bounce.
template<int NCOLS, bool BIASRELU>
__global__ __launch_bounds__(256) void k_mgemm(
    const __half* __restrict__ A, const __half* __restrict__ Wt,
    const float* __restrict__ bias, __half* __restrict__ C, int N)
{
    __shared__ __align__(16) char lds[16384];
    const int tid = threadIdx.x;
    const int row0 = blockIdx.x * 64;

    // stage A tile (64 x 128 fp16), XOR-swizzled rows
    for (int i = tid; i < 1024; i += 256) {
        const int r = i >> 4, ch = i & 15;
        const int row = row0 + r;
        uint4 v = make_uint4(0, 0, 0, 0);
        if (row < N) v = *(const uint4*)(A + (size_t)row * 128 + ch * 8);
        *(uint4*)(lds + r * 256 + ((ch * 16) ^ ((r & 7) << 4))) = v;
    }
    __syncthreads();

    const int w = tid >> 6, l = tid & 63;
    const int lr = l & 15, lk = l >> 4;
    constexpr int NT = NCOLS / 16;
    f32x4 acc[NT] = {};
    const int arow = w * 16 + lr;

#pragma unroll
    for (int kb = 0; kb < 4; ++kb) {
        const f16x8 a = *(const f16x8*)(lds + arow * 256 +
                                        ((kb * 64 + lk * 16) ^ ((arow & 7) << 4)));
#pragma unroll
        for (int nt = 0; nt < NT; ++nt) {
            const f16x8 b = *(const f16x8*)(Wt + (nt * 16 + lr) * 128 + kb * 32 + lk * 8);
            acc[nt] = __builtin_amdgcn_mfma_f32_16x16x32_f16(a, b, acc[nt], 0, 0, 0);
        }
    }
    __syncthreads();   // all waves done reading A tile

    // epilogue: fp16 tile into wave-private LDS region, then coalesced copy
    __half* outw = (__half*)lds + w * 16 * NCOLS;
#pragma unroll
    for (int nt = 0; nt < NT; ++nt) {
        const int col = nt * 16 + lr;
        const float bv = BIASRELU ? bias[col] : 0.f;
#pragma unroll
        for (int i = 0; i < 4; ++i) {
            float v = acc[nt][i];
            if (BIASRELU) v = fmaxf(v + bv, 0.f);
            outw[(lk * 4 + i) * NCOLS + col] = __float2half(v);
        }
    }
    const int rbase = row0 + w * 16;
    constexpr int CHN = 16 * NCOLS / 8;   // 16-B chunks per wave region
    for (int i = l; i < CHN; i += 64) {
        const int row = rbase + (i * 8) / NCOLS;
        if (row < N)
            *(uint4*)(C + (size_t)rbase * NCOLS + i * 8) =
                *(const uint4*)((const char*)outw + i * 16);
    }
}

extern "C" void kernel_launch(void* const* d_in, const int* in_sizes, int n_in,
                              void* d_out, int out_size, void* d_ws, size_t ws_size,
                              hipStream_t stream)
{
    const float* X  = (const float*)d_in[0];
    const int*  src = (const int*)d_in[1];
    const int*  dst = (const int*)d_in[2];
    const float* W1 = (const float*)d_in[3];
    const float* b1 = (const float*)d_in[4];
    const float* W2 = (const float*)d_in[5];
    const float* b2 = (const float*)d_in[6];
    float* out = (float*)d_out;

    const int N = in_sizes[0] / 128;
    const int E = in_sizes[1];
    const int NB = (N + 127) / 128;

    __half* X16   = (__half*)d_ws;                       // N*128 f16
    __half* agg1h = X16 + (size_t)N * 128;               // N*128 f16
    __half* hh    = agg1h + (size_t)N * 128;             // N*128 f16
    __half* m2h   = X16;                                 // alias X16 (dead after agg1)
    unsigned* pairs = (unsigned*)hh;                     // alias hh (dead before gemm1)
    int* edge_src  = (int*)(hh + (size_t)N * 128);       // E
    int* row_start = edge_src + E;                       // N+1
    int* bcnt      = row_start + N + 1;                  // NB
    int* bstart    = bcnt + NB;                          // NB+1
    int* bcursor   = bstart + NB + 1;                    // NB
    __half* W1t    = (__half*)(bcursor + NB);            // 128*128 f16
    __half* W2t    = W1t + 128 * 128;                    // 64*128 f16

    hipMemsetAsync(bcnt, 0, (size_t)NB * sizeof(int), stream);

    // --- CSR build (+ fused X->fp16) ---
    k_bhist_cvt<<<256, 256, 0, stream>>>(dst, bcnt, X, X16, E, NB, (long long)N * 32);
    k_cvtW<<<96, 256, 0, stream>>>(W1, W2, W1t, W2t);
    k_bscan<<<1, 1024, 0, stream>>>(bcnt, bstart, bcursor, NB, E);
    k_binscatter<<<(E + CHUNK - 1) / CHUNK, 256, 0, stream>>>(src, dst, bcursor, pairs, E, NB);
    k_sort<<<NB, 256, 0, stream>>>(pairs, bstart, edge_src, row_start, N, E);

    // --- layer 1: fp16 gather-agg (1/deg folded), MFMA GEMM + bias + relu ---
    k_agg128h<<<(N + 3) / 4, 256, 0, stream>>>(X16, edge_src, row_start, agg1h, N);
    k_mgemm<128, true><<<(N + 63) / 64, 256, 0, stream>>>(agg1h, W1t, b1, hh, N);

    // --- layer 2: MFMA GEMM, fp16 gather-agg with fused epilogue ---
    k_mgemm<64, false><<<(N + 63) / 64, 256, 0, stream>>>(hh, W2t, nullptr, m2h, N);
    k_agg64h<<<(N + 3) / 4, 256, 0, stream>>>(m2h, edge_src, row_start, b2, out, N);
}

// Round 9
// 249.209 us; speedup vs baseline: 9.6971x; 1.0778x over previous
//
#include <hip/hip_runtime.h>
#include <hip/hip_fp16.h>

// GCN: two-level CSR build + wave-per-node fp16 gather agg + fused MFMA GEMMs.
//   1) k_prep: bucket hist (blocks<256) + X->fp16 (all blocks) + W1t/W2t cvt
//   2) k_bscan: bucket exclusive scan
//   3) k_binscatter: LDS hist -> bulk cursor reservation -> low-contention scatter
//   4) k_sort: per-bucket LDS counting sort -> edge_src (dst-sorted), row_start
//   5) k_agg128h: agg1h[n] = fp16((1/deg) * sum X16[src])  (R7-verified form)
//   6) k_mgemm2: m2h = fp16( relu(agg1h@W1+b1) @ W2 )      (fused, barrier-fenced)
//   7) k_agg64h: out[n] = (1/deg) * sum m2h[src] + b2      (R7-verified form)
// Requires N <= 2^17. N = 100000 here.

constexpr int CAP = 6144;
constexpr int CHUNK = 8192;

typedef _Float16 f16x8 __attribute__((ext_vector_type(8)));
typedef float f32x4 __attribute__((ext_vector_type(4)));

__global__ __launch_bounds__(256) void k_prep(
    const int* __restrict__ dst, int* __restrict__ bcnt,
    const float* __restrict__ X, __half* __restrict__ X16,
    const float* __restrict__ W1, const float* __restrict__ W2,
    __half* __restrict__ W1t, __half* __restrict__ W2t,
    int E, int NB, long long n4)
{
    __shared__ int sh[1024];
    const int tid = threadIdx.x;
    if (blockIdx.x < 256) {
        for (int i = tid; i < NB; i += 256) sh[i] = 0;
        __syncthreads();
        for (int e = blockIdx.x * 256 + tid; e < E; e += 256 * 256)
            atomicAdd(&sh[dst[e] >> 7], 1);
        __syncthreads();
        for (int i = tid; i < NB; i += 256) {
            const int v = sh[i];
            if (v) atomicAdd(&bcnt[i], v);
        }
    } else if (blockIdx.x < 352) {
        const int t = (blockIdx.x - 256) * 256 + tid;   // < 24576 exactly
        if (t < 128 * 128) {
            const int k = t >> 7, n = t & 127;
            W1t[n * 128 + k] = __float2half(W1[t]);
        } else {
            const int u = t - 128 * 128;
            const int k = u >> 6, n = u & 63;
            W2t[n * 128 + k] = __float2half(W2[u]);
        }
    }
    for (long long i = (long long)blockIdx.x * 256 + tid; i < n4;
         i += (long long)gridDim.x * 256) {
        const float4 v = ((const float4*)X)[i];
        __half2 h0 = __floats2half2_rn(v.x, v.y);
        __half2 h1 = __floats2half2_rn(v.z, v.w);
        uint2 o;
        o.x = *(const unsigned*)&h0;
        o.y = *(const unsigned*)&h1;
        ((uint2*)X16)[i] = o;
    }
}

__global__ __launch_bounds__(1024) void k_bscan(
    const int* __restrict__ bcnt, int* __restrict__ bstart,
    int* __restrict__ bcursor, int NB, int E)
{
    __shared__ int sh[1024];
    const int t = threadIdx.x;
    const int v = (t < NB) ? bcnt[t] : 0;
    sh[t] = v;
    __syncthreads();
    for (int off = 1; off < 1024; off <<= 1) {
        int u = (t >= off) ? sh[t - off] : 0;
        __syncthreads();
        if (t >= off) sh[t] += u;
        __syncthreads();
    }
    if (t < NB) {
        const int ex = sh[t] - v;
        bstart[t] = ex;
        bcursor[t] = ex;
    }
    if (t == 0) bstart[NB] = E;
}

__global__ __launch_bounds__(256) void k_binscatter(
    const int* __restrict__ src, const int* __restrict__ dst,
    int* __restrict__ bcursor, unsigned* __restrict__ pairs, int E, int NB)
{
    __shared__ int hist[1024];
    __shared__ int base[1024];
    const int b0 = blockIdx.x * CHUNK;
    const int cnt = min(CHUNK, E - b0);
    const int tid = threadIdx.x;

    for (int i = tid; i < NB; i += 256) hist[i] = 0;
    __syncthreads();
    for (int i = tid; i < cnt; i += 256)
        atomicAdd(&hist[dst[b0 + i] >> 7], 1);
    __syncthreads();
    for (int i = tid; i < NB; i += 256) {
        const int c = hist[i];
        base[i] = c ? atomicAdd(&bcursor[i], c) : 0;
    }
    __syncthreads();
    int i = tid;
    for (; i + 768 < cnt; i += 1024) {
        const int d0 = dst[b0 + i], s0 = src[b0 + i];
        const int d1 = dst[b0 + i + 256], s1 = src[b0 + i + 256];
        const int d2 = dst[b0 + i + 512], s2 = src[b0 + i + 512];
        const int d3 = dst[b0 + i + 768], s3 = src[b0 + i + 768];
        const int p0 = atomicAdd(&base[d0 >> 7], 1);
        const int p1 = atomicAdd(&base[d1 >> 7], 1);
        const int p2 = atomicAdd(&base[d2 >> 7], 1);
        const int p3 = atomicAdd(&base[d3 >> 7], 1);
        pairs[p0] = (unsigned)s0 | ((unsigned)(d0 & 127) << 17);
        pairs[p1] = (unsigned)s1 | ((unsigned)(d1 & 127) << 17);
        pairs[p2] = (unsigned)s2 | ((unsigned)(d2 & 127) << 17);
        pairs[p3] = (unsigned)s3 | ((unsigned)(d3 & 127) << 17);
    }
    for (; i < cnt; i += 256) {
        const int d = dst[b0 + i];
        const int p = atomicAdd(&base[d >> 7], 1);
        pairs[p] = (unsigned)src[b0 + i] | ((unsigned)(d & 127) << 17);
    }
}

__global__ __launch_bounds__(256) void k_sort(
    const unsigned* __restrict__ pairs, const int* __restrict__ bstart,
    int* __restrict__ edge_src, int* __restrict__ row_start, int N, int E)
{
    __shared__ unsigned sp[CAP];
    __shared__ int sorted[CAP];
    __shared__ int lcnt[128];
    __shared__ int ls[128];
    const int b = blockIdx.x;
    const int tid = threadIdx.x;
    const int beg = bstart[b], end = bstart[b + 1];
    const int cnt = end - beg;
    const bool fits = (cnt <= CAP);

    if (tid < 128) lcnt[tid] = 0;
    __syncthreads();

    if (fits) {
        for (int i = tid; i < cnt; i += 256) {
            const unsigned p = pairs[beg + i];
            sp[i] = p;
            atomicAdd(&lcnt[p >> 17], 1);
        }
    } else {
        for (int i = tid; i < cnt; i += 256)
            atomicAdd(&lcnt[pairs[beg + i] >> 17], 1);
    }
    __syncthreads();

    if (tid < 128) ls[tid] = lcnt[tid];
    __syncthreads();
    for (int off = 1; off < 128; off <<= 1) {
        int v = 0;
        if (tid < 128 && tid >= off) v = ls[tid - off];
        __syncthreads();
        if (tid < 128 && tid >= off) ls[tid] += v;
        __syncthreads();
    }

    if (tid < 128) {
        const int node = b * 128 + tid;
        if (node <= N) row_start[node] = beg + ls[tid] - lcnt[tid];
    }
    if (b == 0 && tid == 0) row_start[N] = E;
    __syncthreads();

    if (tid < 128) ls[tid] -= lcnt[tid];
    __syncthreads();

    if (fits) {
        for (int i = tid; i < cnt; i += 256) {
            const unsigned p = sp[i];
            const int pos = atomicAdd(&ls[p >> 17], 1);
            sorted[pos] = (int)(p & 0x1FFFFu);
        }
        __syncthreads();
        for (int i = tid; i < cnt; i += 256) edge_src[beg + i] = sorted[i];
    } else {
        for (int i = tid; i < cnt; i += 256) {
            const unsigned p = pairs[beg + i];
            const int pos = atomicAdd(&ls[p >> 17], 1);
            edge_src[beg + pos] = (int)(p & 0x1FFFFu);
        }
    }
}

// Layer-1 agg (R7-verified): wave per node, fp16 gather (128 ch), f32 acc,
// fp16 out with 1/deg folded.
__global__ __launch_bounds__(256) void k_agg128h(
    const __half* __restrict__ M, const int* __restrict__ edge_src,
    const int* __restrict__ row_start, __half* __restrict__ outp, int N)
{
    const int w = (blockIdx.x * 256 + threadIdx.x) >> 6;
    if (w >= N) return;
    const int lane = threadIdx.x & 63;
    const int beg = row_start[w];
    const int end = row_start[w + 1];
    const float inv = 1.0f / fmaxf((float)(end - beg), 1.0f);
    const __half2* M2 = (const __half2*)M;

    float ax = 0.f, ay = 0.f, bx = 0.f, by = 0.f;
    int j = beg;
    for (; j + 3 < end; j += 4) {
        const int s0 = edge_src[j + 0], s1 = edge_src[j + 1];
        const int s2 = edge_src[j + 2], s3 = edge_src[j + 3];
        const float2 v0 = __half22float2(M2[(size_t)s0 * 64 + lane]);
        const float2 v1 = __half22float2(M2[(size_t)s1 * 64 + lane]);
        const float2 v2 = __half22float2(M2[(size_t)s2 * 64 + lane]);
        const float2 v3 = __half22float2(M2[(size_t)s3 * 64 + lane]);
        ax += v0.x + v2.x; ay += v0.y + v2.y;
        bx += v1.x + v3.x; by += v1.y + v3.y;
    }
    for (; j < end; ++j) {
        const float2 v = __half22float2(M2[(size_t)edge_src[j] * 64 + lane]);
        ax += v.x; ay += v.y;
    }
    ((__half2*)(outp + (size_t)w * 128))[lane] =
        __floats2half2_rn((ax + bx) * inv, (ay + by) * inv);
}

// Layer-2 agg (R7-verified): wave per node, 2 edges in flight, fp16 rows, f32 out.
__global__ __launch_bounds__(256) void k_agg64h(
    const __half* __restrict__ M, const int* __restrict__ edge_src,
    const int* __restrict__ row_start, const float* __restrict__ bias,
    float* __restrict__ outp, int N)
{
    const int w = (blockIdx.x * 256 + threadIdx.x) >> 6;
    if (w >= N) return;
    const int lane = threadIdx.x & 63;
    const int half = lane >> 5;
    const int l = lane & 31;
    const int beg = row_start[w];
    const int end = row_start[w + 1];
    const float inv = 1.0f / fmaxf((float)(end - beg), 1.0f);
    const __half2* M2 = (const __half2*)M;

    float ax = 0.f, ay = 0.f, bx = 0.f, by = 0.f;
    int j = beg + half;
    for (; j + 2 < end; j += 4) {
        const int s0 = edge_src[j];
        const int s1 = edge_src[j + 2];
        const float2 v0 = __half22float2(M2[(size_t)s0 * 32 + l]);
        const float2 v1 = __half22float2(M2[(size_t)s1 * 32 + l]);
        ax += v0.x; ay += v0.y;
        bx += v1.x; by += v1.y;
    }
    for (; j < end; j += 2) {
        const float2 v = __half22float2(M2[(size_t)edge_src[j] * 32 + l]);
        ax += v.x; ay += v.y;
    }
    ax += bx; ay += by;
    ax += __shfl_xor(ax, 32);
    ay += __shfl_xor(ay, 32);
    if (half == 0) {
        const float2 b = ((const float2*)bias)[l];
        float2 o;
        o.x = fmaf(ax, inv, b.x);
        o.y = fmaf(ay, inv, b.y);
        ((float2*)(outp + (size_t)w * 64))[l] = o;
    }
}

// Fused MFMA GEMM: m2h = fp16( relu(A@W1 + b1) @ W2 ), 64 rows/block, 4 waves.
// Every LDS write->read phase crossing is fenced with __syncthreads so the
// compiler cannot reorder may-aliasing DS ops (TBAA across __half/f16x8/uint4).
__global__ __launch_bounds__(256) void k_mgemm2(
    const __half* __restrict__ A, const __half* __restrict__ W1t,
    const float* __restrict__ b1, const __half* __restrict__ W2t,
    __half* __restrict__ C, int N)
{
    __shared__ __align__(16) char lds[16384];
    const int tid = threadIdx.x;
    const int row0 = blockIdx.x * 64;

    // phase 1: stage A tile (64 x 128 fp16), XOR-swizzled rows
    for (int i = tid; i < 1024; i += 256) {
        const int r = i >> 4, ch = i & 15;
        const int row = row0 + r;
        uint4 v = make_uint4(0, 0, 0, 0);
        if (row < N) v = *(const uint4*)(A + (size_t)row * 128 + ch * 8);
        *(uint4*)(lds + r * 256 + ((ch * 16) ^ ((r & 7) << 4))) = v;
    }
    __syncthreads();

    const int w = tid >> 6, l = tid & 63;
    const int lr = l & 15, lk = l >> 4;
    const int arow = w * 16 + lr;

    // phase 2: GEMM1
    f32x4 acc1[8] = {};
#pragma unroll
    for (int kb = 0; kb < 4; ++kb) {
        const f16x8 a = *(const f16x8*)(lds + arow * 256 +
                                        ((kb * 64 + lk * 16) ^ ((arow & 7) << 4)));
#pragma unroll
        for (int nt = 0; nt < 8; ++nt) {
            const f16x8 b = *(const f16x8*)(W1t + (nt * 16 + lr) * 128 + kb * 32 + lk * 8);
            acc1[nt] = __builtin_amdgcn_mfma_f32_16x16x32_f16(a, b, acc1[nt], 0, 0, 0);
        }
    }
    __syncthreads();   // A-tile reads done (cross-wave staging)

    // phase 3: h tile (16 x 128 fp16, bias+relu) -> wave-private swizzled LDS
    char* hw = lds + w * 4096;
#pragma unroll
    for (int nt = 0; nt < 8; ++nt) {
        const int col = nt * 16 + lr;
        const float bv = b1[col];
#pragma unroll
        for (int i = 0; i < 4; ++i) {
            const int r = lk * 4 + i;
            const float v = fmaxf(acc1[nt][i] + bv, 0.f);
            *(__half*)(hw + r * 256 + ((col * 2) ^ ((r & 7) << 4))) = __float2half(v);
        }
    }
    __syncthreads();   // fence: h writes ordered before a2 reads

    // phase 4: GEMM2 from LDS h
    f32x4 acc2[4] = {};
#pragma unroll
    for (int kb = 0; kb < 4; ++kb) {
        const f16x8 a2 = *(const f16x8*)(hw + lr * 256 +
                                         ((kb * 64 + lk * 16) ^ ((lr & 7) << 4)));
#pragma unroll
        for (int nt = 0; nt < 4; ++nt) {
            const f16x8 b = *(const f16x8*)(W2t + (nt * 16 + lr) * 128 + kb * 32 + lk * 8);
            acc2[nt] = __builtin_amdgcn_mfma_f32_16x16x32_f16(a2, b, acc2[nt], 0, 0, 0);
        }
    }
    __syncthreads();   // fence: a2 reads done before m2 overwrites h region

    // phase 5: m2 tile (16 x 64 fp16) bounce in the same wave region
#pragma unroll
    for (int nt = 0; nt < 4; ++nt) {
        const int col = nt * 16 + lr;
#pragma unroll
        for (int i = 0; i < 4; ++i) {
            const int r = lk * 4 + i;
            *(__half*)(hw + r * 128 + ((col * 2) ^ ((r & 7) << 4))) = __float2half(acc2[nt][i]);
        }
    }
    __syncthreads();   // fence: m2 writes ordered before copy-out reads

    // phase 6: coalesced copy-out
    const int rbase = row0 + w * 16;
    for (int i = l; i < 128; i += 64) {
        const int r = i >> 3, c = i & 7;
        const int row = rbase + r;
        if (row < N)
            *(uint4*)(C + (size_t)row * 64 + c * 8) =
                *(const uint4*)(hw + r * 128 + ((c * 16) ^ ((r & 7) << 4)));
    }
}

extern "C" void kernel_launch(void* const* d_in, const int* in_sizes, int n_in,
                              void* d_out, int out_size, void* d_ws, size_t ws_size,
                              hipStream_t stream)
{
    const float* X  = (const float*)d_in[0];
    const int*  src = (const int*)d_in[1];
    const int*  dst = (const int*)d_in[2];
    const float* W1 = (const float*)d_in[3];
    const float* b1 = (const float*)d_in[4];
    const float* W2 = (const float*)d_in[5];
    const float* b2 = (const float*)d_in[6];
    float* out = (float*)d_out;

    const int N = in_sizes[0] / 128;
    const int E = in_sizes[1];
    const int NB = (N + 127) / 128;

    __half* X16   = (__half*)d_ws;                       // N*128 f16
    __half* agg1h = X16 + (size_t)N * 128;               // N*128 f16
    __half* scr   = agg1h + (size_t)N * 128;             // N*128 f16 region: pairs
    __half* m2h   = X16;                                 // alias X16 (dead after agg1)
    unsigned* pairs = (unsigned*)scr;                    // E u32 (fits in scr)
    int* edge_src  = (int*)(scr + (size_t)N * 128);      // E
    int* row_start = edge_src + E;                       // N+1
    int* bcnt      = row_start + N + 1;                  // NB
    int* bstart    = bcnt + NB;                          // NB+1
    int* bcursor   = bstart + NB + 1;                    // NB
    __half* W1t    = (__half*)(bcursor + NB);            // 128*128 f16
    __half* W2t    = W1t + 128 * 128;                    // 64*128 f16

    hipMemsetAsync(bcnt, 0, (size_t)NB * sizeof(int), stream);

    // --- prep (hist + X->fp16 + W transposes) & CSR build ---
    k_prep<<<2048, 256, 0, stream>>>(dst, bcnt, X, X16, W1, W2, W1t, W2t,
                                     E, NB, (long long)N * 32);
    k_bscan<<<1, 1024, 0, stream>>>(bcnt, bstart, bcursor, NB, E);
    k_binscatter<<<(E + CHUNK - 1) / CHUNK, 256, 0, stream>>>(src, dst, bcursor, pairs, E, NB);
    k_sort<<<NB, 256, 0, stream>>>(pairs, bstart, edge_src, row_start, N, E);

    // --- layer 1 agg, fused GEMM1+GEMM2, layer 2 agg ---
    k_agg128h<<<(N + 3) / 4, 256, 0, stream>>>(X16, edge_src, row_start, agg1h, N);
    k_mgemm2<<<(N + 63) / 64, 256, 0, stream>>>(agg1h, W1t, b1, W2t, m2h, N);
    k_agg64h<<<(N + 3) / 4, 256, 0, stream>>>(m2h, edge_src, row_start, b2, out, N);
}

// Round 10
// 232.208 us; speedup vs baseline: 10.4071x; 1.0732x over previous
//
#include <hip/hip_runtime.h>
#include <hip/hip_fp16.h>

// GCN: two-level CSR build + wave-per-node fp16 gather agg + fused MFMA GEMMs.
//   1) k_prep: bucket hist (blocks<256) + X->fp16 (all blocks) + W1t/W2t cvt
//   2) k_bscan: bucket exclusive scan
//   3) k_binscatter: LDS hist -> bulk cursor reservation -> low-contention scatter
//   4) k_sort: per-bucket LDS counting sort -> edge_src (dst-sorted), row_start
//   5) k_agg128h: agg1h[n] = fp16((1/deg) * sum X16[src])  (8 gathers in flight)
//   6) k_mgemm2: m2h = fp16( relu(agg1h@W1+b1) @ W2 )      (fused, barrier-fenced)
//   7) k_agg64h: out[n] = (1/deg) * sum m2h[src] + b2      (8 in flight/wave)
// Requires N <= 2^17. N = 100000 here.

constexpr int CAP = 6144;
constexpr int CHUNK = 8192;

typedef _Float16 f16x8 __attribute__((ext_vector_type(8)));
typedef float f32x4 __attribute__((ext_vector_type(4)));

__global__ __launch_bounds__(256) void k_prep(
    const int* __restrict__ dst, int* __restrict__ bcnt,
    const float* __restrict__ X, __half* __restrict__ X16,
    const float* __restrict__ W1, const float* __restrict__ W2,
    __half* __restrict__ W1t, __half* __restrict__ W2t,
    int E, int NB, long long n4)
{
    __shared__ int sh[1024];
    const int tid = threadIdx.x;
    if (blockIdx.x < 256) {
        for (int i = tid; i < NB; i += 256) sh[i] = 0;
        __syncthreads();
        for (int e = blockIdx.x * 256 + tid; e < E; e += 256 * 256)
            atomicAdd(&sh[dst[e] >> 7], 1);
        __syncthreads();
        for (int i = tid; i < NB; i += 256) {
            const int v = sh[i];
            if (v) atomicAdd(&bcnt[i], v);
        }
    } else if (blockIdx.x < 352) {
        const int t = (blockIdx.x - 256) * 256 + tid;   // < 24576 exactly
        if (t < 128 * 128) {
            const int k = t >> 7, n = t & 127;
            W1t[n * 128 + k] = __float2half(W1[t]);
        } else {
            const int u = t - 128 * 128;
            const int k = u >> 6, n = u & 63;
            W2t[n * 128 + k] = __float2half(W2[u]);
        }
    }
    for (long long i = (long long)blockIdx.x * 256 + tid; i < n4;
         i += (long long)gridDim.x * 256) {
        const float4 v = ((const float4*)X)[i];
        __half2 h0 = __floats2half2_rn(v.x, v.y);
        __half2 h1 = __floats2half2_rn(v.z, v.w);
        uint2 o;
        o.x = *(const unsigned*)&h0;
        o.y = *(const unsigned*)&h1;
        ((uint2*)X16)[i] = o;
    }
}

__global__ __launch_bounds__(1024) void k_bscan(
    const int* __restrict__ bcnt, int* __restrict__ bstart,
    int* __restrict__ bcursor, int NB, int E)
{
    __shared__ int sh[1024];
    const int t = threadIdx.x;
    const int v = (t < NB) ? bcnt[t] : 0;
    sh[t] = v;
    __syncthreads();
    for (int off = 1; off < 1024; off <<= 1) {
        int u = (t >= off) ? sh[t - off] : 0;
        __syncthreads();
        if (t >= off) sh[t] += u;
        __syncthreads();
    }
    if (t < NB) {
        const int ex = sh[t] - v;
        bstart[t] = ex;
        bcursor[t] = ex;
    }
    if (t == 0) bstart[NB] = E;
}

__global__ __launch_bounds__(256) void k_binscatter(
    const int* __restrict__ src, const int* __restrict__ dst,
    int* __restrict__ bcursor, unsigned* __restrict__ pairs, int E, int NB)
{
    __shared__ int hist[1024];
    __shared__ int base[1024];
    const int b0 = blockIdx.x * CHUNK;
    const int cnt = min(CHUNK, E - b0);
    const int tid = threadIdx.x;

    for (int i = tid; i < NB; i += 256) hist[i] = 0;
    __syncthreads();
    for (int i = tid; i < cnt; i += 256)
        atomicAdd(&hist[dst[b0 + i] >> 7], 1);
    __syncthreads();
    for (int i = tid; i < NB; i += 256) {
        const int c = hist[i];
        base[i] = c ? atomicAdd(&bcursor[i], c) : 0;
    }
    __syncthreads();
    int i = tid;
    for (; i + 768 < cnt; i += 1024) {
        const int d0 = dst[b0 + i], s0 = src[b0 + i];
        const int d1 = dst[b0 + i + 256], s1 = src[b0 + i + 256];
        const int d2 = dst[b0 + i + 512], s2 = src[b0 + i + 512];
        const int d3 = dst[b0 + i + 768], s3 = src[b0 + i + 768];
        const int p0 = atomicAdd(&base[d0 >> 7], 1);
        const int p1 = atomicAdd(&base[d1 >> 7], 1);
        const int p2 = atomicAdd(&base[d2 >> 7], 1);
        const int p3 = atomicAdd(&base[d3 >> 7], 1);
        pairs[p0] = (unsigned)s0 | ((unsigned)(d0 & 127) << 17);
        pairs[p1] = (unsigned)s1 | ((unsigned)(d1 & 127) << 17);
        pairs[p2] = (unsigned)s2 | ((unsigned)(d2 & 127) << 17);
        pairs[p3] = (unsigned)s3 | ((unsigned)(d3 & 127) << 17);
    }
    for (; i < cnt; i += 256) {
        const int d = dst[b0 + i];
        const int p = atomicAdd(&base[d >> 7], 1);
        pairs[p] = (unsigned)src[b0 + i] | ((unsigned)(d & 127) << 17);
    }
}

__global__ __launch_bounds__(256) void k_sort(
    const unsigned* __restrict__ pairs, const int* __restrict__ bstart,
    int* __restrict__ edge_src, int* __restrict__ row_start, int N, int E)
{
    __shared__ unsigned sp[CAP];
    __shared__ int sorted[CAP];
    __shared__ int lcnt[128];
    __shared__ int ls[128];
    const int b = blockIdx.x;
    const int tid = threadIdx.x;
    const int beg = bstart[b], end = bstart[b + 1];
    const int cnt = end - beg;
    const bool fits = (cnt <= CAP);

    if (tid < 128) lcnt[tid] = 0;
    __syncthreads();

    if (fits) {
        for (int i = tid; i < cnt; i += 256) {
            const unsigned p = pairs[beg + i];
            sp[i] = p;
            atomicAdd(&lcnt[p >> 17], 1);
        }
    } else {
        for (int i = tid; i < cnt; i += 256)
            atomicAdd(&lcnt[pairs[beg + i] >> 17], 1);
    }
    __syncthreads();

    if (tid < 128) ls[tid] = lcnt[tid];
    __syncthreads();
    for (int off = 1; off < 128; off <<= 1) {
        int v = 0;
        if (tid < 128 && tid >= off) v = ls[tid - off];
        __syncthreads();
        if (tid < 128 && tid >= off) ls[tid] += v;
        __syncthreads();
    }

    if (tid < 128) {
        const int node = b * 128 + tid;
        if (node <= N) row_start[node] = beg + ls[tid] - lcnt[tid];
    }
    if (b == 0 && tid == 0) row_start[N] = E;
    __syncthreads();

    if (tid < 128) ls[tid] -= lcnt[tid];
    __syncthreads();

    if (fits) {
        for (int i = tid; i < cnt; i += 256) {
            const unsigned p = sp[i];
            const int pos = atomicAdd(&ls[p >> 17], 1);
            sorted[pos] = (int)(p & 0x1FFFFu);
        }
        __syncthreads();
        for (int i = tid; i < cnt; i += 256) edge_src[beg + i] = sorted[i];
    } else {
        for (int i = tid; i < cnt; i += 256) {
            const unsigned p = pairs[beg + i];
            const int pos = atomicAdd(&ls[p >> 17], 1);
            edge_src[beg + pos] = (int)(p & 0x1FFFFu);
        }
    }
}

// Layer-1 agg: wave per node, fp16 gather (128 ch), f32 acc, fp16 out w/ 1/deg.
// 8 row-gathers in flight per wave.
__global__ __launch_bounds__(256) void k_agg128h(
    const __half* __restrict__ M, const int* __restrict__ edge_src,
    const int* __restrict__ row_start, __half* __restrict__ outp, int N)
{
    const int w = (blockIdx.x * 256 + threadIdx.x) >> 6;
    if (w >= N) return;
    const int lane = threadIdx.x & 63;
    const int beg = row_start[w];
    const int end = row_start[w + 1];
    const float inv = 1.0f / fmaxf((float)(end - beg), 1.0f);
    const __half2* M2 = (const __half2*)M;

    float ax = 0.f, ay = 0.f, bx = 0.f, by = 0.f;
    int j = beg;
    for (; j + 7 < end; j += 8) {
        const int s0 = edge_src[j + 0], s1 = edge_src[j + 1];
        const int s2 = edge_src[j + 2], s3 = edge_src[j + 3];
        const int s4 = edge_src[j + 4], s5 = edge_src[j + 5];
        const int s6 = edge_src[j + 6], s7 = edge_src[j + 7];
        const float2 v0 = __half22float2(M2[(size_t)s0 * 64 + lane]);
        const float2 v1 = __half22float2(M2[(size_t)s1 * 64 + lane]);
        const float2 v2 = __half22float2(M2[(size_t)s2 * 64 + lane]);
        const float2 v3 = __half22float2(M2[(size_t)s3 * 64 + lane]);
        const float2 v4 = __half22float2(M2[(size_t)s4 * 64 + lane]);
        const float2 v5 = __half22float2(M2[(size_t)s5 * 64 + lane]);
        const float2 v6 = __half22float2(M2[(size_t)s6 * 64 + lane]);
        const float2 v7 = __half22float2(M2[(size_t)s7 * 64 + lane]);
        ax += v0.x + v2.x + v4.x + v6.x;
        ay += v0.y + v2.y + v4.y + v6.y;
        bx += v1.x + v3.x + v5.x + v7.x;
        by += v1.y + v3.y + v5.y + v7.y;
    }
    for (; j + 3 < end; j += 4) {
        const int s0 = edge_src[j + 0], s1 = edge_src[j + 1];
        const int s2 = edge_src[j + 2], s3 = edge_src[j + 3];
        const float2 v0 = __half22float2(M2[(size_t)s0 * 64 + lane]);
        const float2 v1 = __half22float2(M2[(size_t)s1 * 64 + lane]);
        const float2 v2 = __half22float2(M2[(size_t)s2 * 64 + lane]);
        const float2 v3 = __half22float2(M2[(size_t)s3 * 64 + lane]);
        ax += v0.x + v2.x; ay += v0.y + v2.y;
        bx += v1.x + v3.x; by += v1.y + v3.y;
    }
    for (; j < end; ++j) {
        const float2 v = __half22float2(M2[(size_t)edge_src[j] * 64 + lane]);
        ax += v.x; ay += v.y;
    }
    ((__half2*)(outp + (size_t)w * 128))[lane] =
        __floats2half2_rn((ax + bx) * inv, (ay + by) * inv);
}

// Layer-2 agg: wave per node, half-wave per edge, 4 in flight per half-wave
// (8/wave), f32 acc, combine via shfl_xor(32), epi = *inv + b2.
__global__ __launch_bounds__(256) void k_agg64h(
    const __half* __restrict__ M, const int* __restrict__ edge_src,
    const int* __restrict__ row_start, const float* __restrict__ bias,
    float* __restrict__ outp, int N)
{
    const int w = (blockIdx.x * 256 + threadIdx.x) >> 6;
    if (w >= N) return;
    const int lane = threadIdx.x & 63;
    const int half = lane >> 5;
    const int l = lane & 31;
    const int beg = row_start[w];
    const int end = row_start[w + 1];
    const float inv = 1.0f / fmaxf((float)(end - beg), 1.0f);
    const __half2* M2 = (const __half2*)M;

    float ax = 0.f, ay = 0.f, bx = 0.f, by = 0.f;
    int j = beg + half;
    for (; j + 6 < end; j += 8) {
        const int s0 = edge_src[j];
        const int s1 = edge_src[j + 2];
        const int s2 = edge_src[j + 4];
        const int s3 = edge_src[j + 6];
        const float2 v0 = __half22float2(M2[(size_t)s0 * 32 + l]);
        const float2 v1 = __half22float2(M2[(size_t)s1 * 32 + l]);
        const float2 v2 = __half22float2(M2[(size_t)s2 * 32 + l]);
        const float2 v3 = __half22float2(M2[(size_t)s3 * 32 + l]);
        ax += v0.x + v2.x; ay += v0.y + v2.y;
        bx += v1.x + v3.x; by += v1.y + v3.y;
    }
    for (; j < end; j += 2) {
        const float2 v = __half22float2(M2[(size_t)edge_src[j] * 32 + l]);
        ax += v.x; ay += v.y;
    }
    ax += bx; ay += by;
    ax += __shfl_xor(ax, 32);
    ay += __shfl_xor(ay, 32);
    if (half == 0) {
        const float2 b = ((const float2*)bias)[l];
        float2 o;
        o.x = fmaf(ax, inv, b.x);
        o.y = fmaf(ay, inv, b.y);
        ((float2*)(outp + (size_t)w * 64))[l] = o;
    }
}

// Fused MFMA GEMM: m2h = fp16( relu(A@W1 + b1) @ W2 ), 64 rows/block, 4 waves.
// Every LDS write->read phase crossing is fenced with __syncthreads so the
// compiler cannot reorder may-aliasing DS ops (TBAA across __half/f16x8/uint4).
__global__ __launch_bounds__(256) void k_mgemm2(
    const __half* __restrict__ A, const __half* __restrict__ W1t,
    const float* __restrict__ b1, const __half* __restrict__ W2t,
    __half* __restrict__ C, int N)
{
    __shared__ __align__(16) char lds[16384];
    const int tid = threadIdx.x;
    const int row0 = blockIdx.x * 64;

    // phase 1: stage A tile (64 x 128 fp16), XOR-swizzled rows
    for (int i = tid; i < 1024; i += 256) {
        const int r = i >> 4, ch = i & 15;
        const int row = row0 + r;
        uint4 v = make_uint4(0, 0, 0, 0);
        if (row < N) v = *(const uint4*)(A + (size_t)row * 128 + ch * 8);
        *(uint4*)(lds + r * 256 + ((ch * 16) ^ ((r & 7) << 4))) = v;
    }
    __syncthreads();

    const int w = tid >> 6, l = tid & 63;
    const int lr = l & 15, lk = l >> 4;
    const int arow = w * 16 + lr;

    // phase 2: GEMM1
    f32x4 acc1[8] = {};
#pragma unroll
    for (int kb = 0; kb < 4; ++kb) {
        const f16x8 a = *(const f16x8*)(lds + arow * 256 +
                                        ((kb * 64 + lk * 16) ^ ((arow & 7) << 4)));
#pragma unroll
        for (int nt = 0; nt < 8; ++nt) {
            const f16x8 b = *(const f16x8*)(W1t + (nt * 16 + lr) * 128 + kb * 32 + lk * 8);
            acc1[nt] = __builtin_amdgcn_mfma_f32_16x16x32_f16(a, b, acc1[nt], 0, 0, 0);
        }
    }
    __syncthreads();   // A-tile reads done (cross-wave staging)

    // phase 3: h tile (16 x 128 fp16, bias+relu) -> wave-private swizzled LDS
    char* hw = lds + w * 4096;
#pragma unroll
    for (int nt = 0; nt < 8; ++nt) {
        const int col = nt * 16 + lr;
        const float bv = b1[col];
#pragma unroll
        for (int i = 0; i < 4; ++i) {
            const int r = lk * 4 + i;
            const float v = fmaxf(acc1[nt][i] + bv, 0.f);
            *(__half*)(hw + r * 256 + ((col * 2) ^ ((r & 7) << 4))) = __float2half(v);
        }
    }
    __syncthreads();   // fence: h writes ordered before a2 reads

    // phase 4: GEMM2 from LDS h
    f32x4 acc2[4] = {};
#pragma unroll
    for (int kb = 0; kb < 4; ++kb) {
        const f16x8 a2 = *(const f16x8*)(hw + lr * 256 +
                                         ((kb * 64 + lk * 16) ^ ((lr & 7) << 4)));
#pragma unroll
        for (int nt = 0; nt < 4; ++nt) {
            const f16x8 b = *(const f16x8*)(W2t + (nt * 16 + lr) * 128 + kb * 32 + lk * 8);
            acc2[nt] = __builtin_amdgcn_mfma_f32_16x16x32_f16(a2, b, acc2[nt], 0, 0, 0);
        }
    }
    __syncthreads();   // fence: a2 reads done before m2 overwrites h region

    // phase 5: m2 tile (16 x 64 fp16) bounce in the same wave region
#pragma unroll
    for (int nt = 0; nt < 4; ++nt) {
        const int col = nt * 16 + lr;
#pragma unroll
        for (int i = 0; i < 4; ++i) {
            const int r = lk * 4 + i;
            *(__half*)(hw + r * 128 + ((col * 2) ^ ((r & 7) << 4))) = __float2half(acc2[nt][i]);
        }
    }
    __syncthreads();   // fence: m2 writes ordered before copy-out reads

    // phase 6: coalesced copy-out
    const int rbase = row0 + w * 16;
    for (int i = l; i < 128; i += 64) {
        const int r = i >> 3, c = i & 7;
        const int row = rbase + r;
        if (row < N)
            *(uint4*)(C + (size_t)row * 64 + c * 8) =
                *(const uint4*)(hw + r * 128 + ((c * 16) ^ ((r & 7) << 4)));
    }
}

extern "C" void kernel_launch(void* const* d_in, const int* in_sizes, int n_in,
                              void* d_out, int out_size, void* d_ws, size_t ws_size,
                              hipStream_t stream)
{
    const float* X  = (const float*)d_in[0];
    const int*  src = (const int*)d_in[1];
    const int*  dst = (const int*)d_in[2];
    const float* W1 = (const float*)d_in[3];
    const float* b1 = (const float*)d_in[4];
    const float* W2 = (const float*)d_in[5];
    const float* b2 = (const float*)d_in[6];
    float* out = (float*)d_out;

    const int N = in_sizes[0] / 128;
    const int E = in_sizes[1];
    const int NB = (N + 127) / 128;

    __half* X16   = (__half*)d_ws;                       // N*128 f16
    __half* agg1h = X16 + (size_t)N * 128;               // N*128 f16
    __half* scr   = agg1h + (size_t)N * 128;             // N*128 f16 region: pairs
    __half* m2h   = X16;                                 // alias X16 (dead after agg1)
    unsigned* pairs = (unsigned*)scr;                    // E u32 (fits in scr)
    int* edge_src  = (int*)(scr + (size_t)N * 128);      // E
    int* row_start = edge_src + E;                       // N+1
    int* bcnt      = row_start + N + 1;                  // NB
    int* bstart    = bcnt + NB;                          // NB+1
    int* bcursor   = bstart + NB + 1;                    // NB
    __half* W1t    = (__half*)(bcursor + NB);            // 128*128 f16
    __half* W2t    = W1t + 128 * 128;                    // 64*128 f16

    hipMemsetAsync(bcnt, 0, (size_t)NB * sizeof(int), stream);

    // --- prep (hist + X->fp16 + W transposes) & CSR build ---
    k_prep<<<2048, 256, 0, stream>>>(dst, bcnt, X, X16, W1, W2, W1t, W2t,
                                     E, NB, (long long)N * 32);
    k_bscan<<<1, 1024, 0, stream>>>(bcnt, bstart, bcursor, NB, E);
    k_binscatter<<<(E + CHUNK - 1) / CHUNK, 256, 0, stream>>>(src, dst, bcursor, pairs, E, NB);
    k_sort<<<NB, 256, 0, stream>>>(pairs, bstart, edge_src, row_start, N, E);

    // --- layer 1 agg, fused GEMM1+GEMM2, layer 2 agg ---
    k_agg128h<<<(N + 3) / 4, 256, 0, stream>>>(X16, edge_src, row_start, agg1h, N);
    k_mgemm2<<<(N + 63) / 64, 256, 0, stream>>>(agg1h, W1t, b1, W2t, m2h, N);
    k_agg64h<<<(N + 3) / 4, 256, 0, stream>>>(m2h, edge_src, row_start, b2, out, N);
}